// Round 7
// baseline (235.477 us; speedup 1.0000x reference)
//
#include <hip/hip_runtime.h>
#include <hip/hip_bf16.h>

#define K_CODES 512
#define CDIM    256
#define HW      1024
#define NBATCH  64
#define SZ      260   // validated LDS stride

typedef float  f32x16 __attribute__((ext_vector_type(16)));
typedef short  bf16x8 __attribute__((ext_vector_type(8)));

typedef __attribute__((address_space(1))) const unsigned int gld_src_t;
typedef __attribute__((address_space(3))) unsigned int       gld_dst_t;

__device__ __forceinline__ unsigned short f2bf(float x) {
    unsigned u = __float_as_uint(x);
    unsigned r = (u + 0x7FFFu + ((u >> 16) & 1u)) >> 16;   // RNE
    return (unsigned short)r;
}

// ---------------- Prep: en[512] fp32 + codebook bf16 ----------------
__global__ __launch_bounds__(64) void vq_prep(const float* __restrict__ cb,
                                              float* __restrict__ enorm,
                                              unsigned short* __restrict__ cb16) {
    int k = blockIdx.x;
    int l = threadIdx.x;
    float4 v = *reinterpret_cast<const float4*>(cb + (size_t)k * CDIM + l * 4);
    float s = (v.x * v.x + v.y * v.y) + (v.z * v.z + v.w * v.w);
#pragma unroll
    for (int off = 1; off < 64; off <<= 1) s += __shfl_xor(s, off, 64);
    if (l == 0) enorm[k] = s;
    ushort4 o;
    o.x = f2bf(v.x); o.y = f2bf(v.y); o.z = f2bf(v.z); o.w = f2bf(v.w);
    *reinterpret_cast<ushort4*>(cb16 + (size_t)k * CDIM + l * 4) = o;
}

__global__ __launch_bounds__(64) void vq_enorm(const float* __restrict__ cb,
                                               float* __restrict__ enorm) {
    int k = blockIdx.x;
    int l = threadIdx.x;
    float4 v = *reinterpret_cast<const float4*>(cb + (size_t)k * CDIM + l * 4);
    float s = (v.x * v.x + v.y * v.y) + (v.z * v.z + v.w * v.w);
#pragma unroll
    for (int off = 1; off < 64; off <<= 1) s += __shfl_xor(s, off, 64);
    if (l == 0) enorm[k] = s;
}

// ---------------- zn: bit-identical row norms for all 65536 rows ----------------
// Staging layout/values and chain order identical to the validated argmin kernel.
__global__ __launch_bounds__(256) void vq_zn(const float* __restrict__ z,
                                             float* __restrict__ zn_out) {
    __shared__ float zs[64][SZ];
    const int t  = threadIdx.x;
    const int r0 = blockIdx.x * 64;
    const int b  = r0 >> 10;
    const int n0 = r0 & 1023;
    const float* zb = z + (size_t)b * CDIM * HW;

#pragma unroll
    for (int p = 0; p < 16; ++p) {
        int lin = p * 256 + t;
        int c   = lin >> 4;
        int i0  = (lin & 15) << 2;
        float4 v = *reinterpret_cast<const float4*>(zb + (size_t)c * HW + n0 + i0);
        zs[i0 + 0][c] = v.x; zs[i0 + 1][c] = v.y;
        zs[i0 + 2][c] = v.z; zs[i0 + 3][c] = v.w;
    }
    __syncthreads();
    if (t < 64) {
        float s0 = 0.f, s1 = 0.f, s2 = 0.f, s3 = 0.f;
        for (int c = 0; c < CDIM; c += 4) {
            float4 v = *reinterpret_cast<const float4*>(&zs[t][c]);
            s0 += v.x * v.x; s1 += v.y * v.y; s2 += v.z * v.z; s3 += v.w * v.w;
        }
        zn_out[r0 + t] = (s0 + s1) + (s2 + s3);
    }
}

// ---------------- Pass 1: single-sweep MFMA filter, reg top-6, async es pipeline ----------------
// 128 rows/block, 256 thr (4 waves x 32 rows). 16 phases of 32 codes.
// Emits: cnt==1 rows -> idx directly; multi rows -> compacted global worklist
// (row | cnt<<16); overflow rows (cnt>12 possible) -> oflist (full-scan kernel).
__global__ __launch_bounds__(256, 2) void vq_pass1(const float* __restrict__ z,
                                                   const unsigned short* __restrict__ cb16,
                                                   unsigned short* __restrict__ codes_out,
                                                   int* __restrict__ idx_out,
                                                   unsigned* __restrict__ mlist,
                                                   unsigned* __restrict__ oflist,
                                                   unsigned* __restrict__ ctr) {
    __shared__ __align__(16) char smem[70144];
    unsigned short* zs    = (unsigned short*)smem;            // 64KB transient
    unsigned*       zsw   = (unsigned*)smem;
    unsigned short* es    = (unsigned short*)smem;            // reuse: 4 x 16KB ring
    unsigned short* candl = (unsigned short*)(smem + 65536);  // 128*16 u16
    unsigned*       cntl  = (unsigned*)(smem + 69632);        // 128 u32

    const int t = threadIdx.x;
    const int l = t & 63, w = t >> 6;          // 4 waves
    const int r0 = blockIdx.x << 7;            // 128 rows/block
    const int b  = r0 >> 10, n0 = r0 & 1023;
    const float* zb = z + (size_t)b * (CDIM * HW);

    // ---- stage z: transpose + bf16 (identical bit-path to validated rounds)
#pragma unroll
    for (int p = 0; p < 16; ++p) {
        int lin = (p << 8) + t;
        int c2  = lin >> 5;          // 0..127 (k-pairs)
        int iq  = lin & 31;          // 0..31  (row-quads)
        const float* g0 = zb + (size_t)(2 * c2) * HW + n0 + (iq << 2);
        float4 a  = *reinterpret_cast<const float4*>(g0);
        float4 bb = *reinterpret_cast<const float4*>(g0 + HW);
        int up = (((c2 >> 2) ^ (iq & 7)) << 2) + (c2 & 3);
        const float* ap = &a.x; const float* bp = &bb.x;
#pragma unroll
        for (int j = 0; j < 4; ++j) {
            unsigned pk = (unsigned)f2bf(ap[j]) | ((unsigned)f2bf(bp[j]) << 16);
            zsw[((iq << 2) + j) * 128 + up] = pk;
        }
    }
    __syncthreads();

    // ---- B-frags (z rows) into registers (identical to validated rounds)
    const int lrow = l & 31, lh = l >> 5;
    const int lf  = (lrow >> 2) & 7;
    const int row = (w << 5) + lrow;           // 0..127
    bf16x8 zf[16];
#pragma unroll
    for (int s = 0; s < 16; ++s) {
        int u = (2 * s + lh) ^ lf;
        zf[s] = *reinterpret_cast<const bf16x8*>(&zs[row * 256 + (u << 3)]);
    }
    float sa = 0.f;
#pragma unroll
    for (int s = 0; s < 16; ++s)
#pragma unroll
        for (int j = 0; j < 8; ++j)
            sa += fabsf(__uint_as_float(((unsigned)(unsigned short)zf[s][j]) << 16));
    sa += __shfl_xor(sa, 32, 64);

    __syncthreads();   // all zs reads done -> es ring may reuse region

    // ---- async es stager: wave w fills chunks w*4..w*4+3 (1KB each) of a phase
    const int lq = l & 31, lhh = l >> 5;
    auto ISSUE = [&](int ph) {
#pragma unroll
        for (int j = 0; j < 4; ++j) {
            int chunk = (w << 2) + j;
            int lc    = (chunk << 1) + lhh;        // local code 0..31
            int su    = (lq - lc) & 31;            // pre-rotated source unit
            const unsigned short* gp = cb16 + (((size_t)((ph << 5) + lc)) << 8) + (su << 3);
            char* lp = smem + (((ph & 3) << 14) + (chunk << 10));
            __builtin_amdgcn_global_load_lds((gld_src_t*)gp, (gld_dst_t*)lp, 16, 0, 0);
        }
    };

    ISSUE(0); ISSUE(1);
    asm volatile("s_waitcnt vmcnt(4)" ::: "memory");
    __builtin_amdgcn_s_barrier();

    const float padf = sa * 1.7e-5f + 6.0e-4f;     // validated margin
    float runmax = -3.4e38f;
    float s0 = -3.4e38f, s1 = -3.4e38f, s2 = -3.4e38f,
          s3 = -3.4e38f, s4 = -3.4e38f, s5 = -3.4e38f;
    int   k0 = 0, k1 = 0, k2 = 0, k3 = 0, k4 = 0, k5 = 0;

    for (int p = 0; p < 16; ++p) {
        if (p + 2 < 16) ISSUE(p + 2);
        if (p >= 1) {
            if (p < 14)       asm volatile("s_waitcnt vmcnt(8)" ::: "memory");
            else if (p == 14) asm volatile("s_waitcnt vmcnt(4)" ::: "memory");
            else              asm volatile("s_waitcnt vmcnt(0)" ::: "memory");
            __builtin_amdgcn_s_barrier();
        }
        const unsigned short* eb = es + ((p & 3) << 13);

        f32x16 accA = {0.f,0.f,0.f,0.f,0.f,0.f,0.f,0.f,0.f,0.f,0.f,0.f,0.f,0.f,0.f,0.f};
        f32x16 accB = accA;
#pragma unroll
        for (int s = 0; s < 16; s += 2) {
            int u0 = (2 * s + lh + lrow) & 31;
            int u1 = (2 * s + 2 + lh + lrow) & 31;
            bf16x8 a0 = *reinterpret_cast<const bf16x8*>(&eb[(lrow << 8) + (u0 << 3)]);
            bf16x8 a1 = *reinterpret_cast<const bf16x8*>(&eb[(lrow << 8) + (u1 << 3)]);
            accA = __builtin_amdgcn_mfma_f32_32x32x16_bf16(a0, zf[s],     accA, 0, 0, 0);
            accB = __builtin_amdgcn_mfma_f32_32x32x16_bf16(a1, zf[s + 1], accB, 0, 0, 0);
        }

        float v[16]; float pm = -3.4e38f;
#pragma unroll
        for (int i = 0; i < 16; ++i) { v[i] = accA[i] + accB[i]; pm = fmaxf(pm, v[i]); }

        if (pm >= runmax - padf) {
            int cbase = (p << 5) + 4 * lh;
#pragma unroll
            for (int i = 0; i < 16; ++i) {
                float vv = v[i];
                int   cc = cbase + (i & 3) + 8 * (i >> 2);
                bool c5 = vv > s5, c4 = vv > s4, c3 = vv > s3,
                     c2 = vv > s2, c1 = vv > s1, c0 = vv > s0;
                s5 = c5 ? (c4 ? s4 : vv) : s5;  k5 = c5 ? (c4 ? k4 : cc) : k5;
                s4 = c4 ? (c3 ? s3 : vv) : s4;  k4 = c4 ? (c3 ? k3 : cc) : k4;
                s3 = c3 ? (c2 ? s2 : vv) : s3;  k3 = c3 ? (c2 ? k2 : cc) : k3;
                s2 = c2 ? (c1 ? s1 : vv) : s2;  k2 = c2 ? (c1 ? k1 : cc) : k2;
                s1 = c1 ? (c0 ? s0 : vv) : s1;  k1 = c1 ? (c0 ? k0 : cc) : k1;
                s0 = c0 ? vv : s0;              k0 = c0 ? cc : k0;
            }
        }
        runmax = fmaxf(runmax, pm);
    }

    // ---- extraction: merge lane pair (lh 0/1), filter by final threshold
    float rowmax = fmaxf(runmax, __shfl_xor(runmax, 32, 64));
    const float thr = rowmax - padf;
    float p0 = __shfl_xor(s0, 32, 64), p1 = __shfl_xor(s1, 32, 64),
          p2 = __shfl_xor(s2, 32, 64), p3 = __shfl_xor(s3, 32, 64),
          p4 = __shfl_xor(s4, 32, 64), p5 = __shfl_xor(s5, 32, 64);
    int   q0 = __shfl_xor(k0, 32, 64), q1 = __shfl_xor(k1, 32, 64),
          q2 = __shfl_xor(k2, 32, 64), q3 = __shfl_xor(k3, 32, 64),
          q4 = __shfl_xor(k4, 32, 64), q5 = __shfl_xor(k5, 32, 64);

    if (lh == 0) {
        int cnt = 0;
#define VQ_EMIT(SV, KV) do { if ((SV) >= thr) { candl[(row << 4) + cnt] = (unsigned short)(KV); ++cnt; } } while (0)
        VQ_EMIT(s0, k0); VQ_EMIT(s1, k1); VQ_EMIT(s2, k2);
        VQ_EMIT(s3, k3); VQ_EMIT(s4, k4); VQ_EMIT(s5, k5);
        VQ_EMIT(p0, q0); VQ_EMIT(p1, q1); VQ_EMIT(p2, q2);
        VQ_EMIT(p3, q3); VQ_EMIT(p4, q4); VQ_EMIT(p5, q5);
#undef VQ_EMIT
        bool of = (s5 >= thr) || (p5 >= thr);   // possible 7th candidate in a half
        cntl[row] = of ? 17u : (unsigned)cnt;
    }
    __syncthreads();

    if (t < 128) {
        unsigned c = cntl[t];
        if (c == 1u) idx_out[r0 + t] = (int)candl[t << 4];
        bool multi = (c >= 2u && c <= 16u);
        bool ofl   = (c > 16u);
        unsigned long long m = __ballot(multi);
        int lane = t & 63;
        int rank = __popcll(m & ((1ull << lane) - 1ull));
        int tot  = __popcll(m);
        unsigned base = 0;
        if (lane == 0 && tot) base = atomicAdd(&ctr[0], (unsigned)tot);
        base = __shfl(base, 0, 64);
        if (multi) mlist[base + rank] = (unsigned)(r0 + t) | (c << 16);
        if (ofl) {
            unsigned pos = atomicAdd(&ctr[1], 1u);
            if (pos < 4096u) oflist[pos] = (unsigned)(r0 + t);
        }
    }
    reinterpret_cast<uint4*>(codes_out + ((size_t)r0 << 4))[t] =
        reinterpret_cast<const uint4*>(candl)[t];
}

// ---------------- Pass 2: exact fp32 rescore, one candidate-chain per thread ----------------
// No LDS, no barriers. Thread i: worklist pair i>>1, side i&1; candidates
// j = side, side+2, ...; pair-merge via shfl_xor(1). Chain order byte-identical
// to the validated kernel (z read in ascending-c order, cb float4, seq FMA).
__global__ __launch_bounds__(256) void vq_rescore2(const float* __restrict__ z,
                                                   const float* __restrict__ cb,
                                                   const float* __restrict__ enb,
                                                   const float* __restrict__ znb,
                                                   const unsigned short* __restrict__ codes_in,
                                                   const unsigned* __restrict__ ctr,
                                                   const unsigned* __restrict__ mlist,
                                                   int* __restrict__ idx_out) {
    const unsigned N = ctr[0];
    const unsigned total = N * 2u;
    unsigned i = blockIdx.x * 256u + threadIdx.x;
    for (; i < total; i += gridDim.x * 256u) {
        unsigned e   = mlist[i >> 1];
        int side     = (int)(i & 1u);
        int row      = (int)(e & 0xFFFFu);
        int cnt      = (int)(e >> 16);
        const float* zp = z + (((size_t)(row >> 10)) << 18) + (row & 1023);
        const float  zn = znb[row];
        unsigned long long pk = 0xFFFFFFFFFFFFFFFFull;

        for (int j = side; j < cnt; j += 2) {
            int code = (int)codes_in[((size_t)row << 4) + j];
            const float* ep = cb + ((size_t)code << 8);
            float acc = 0.f;
#pragma unroll 8
            for (int u = 0; u < 64; ++u) {
                float4 ev = *reinterpret_cast<const float4*>(ep + (u << 2));
                float zx = zp[(size_t)(4 * u + 0) << 10];
                float zy = zp[(size_t)(4 * u + 1) << 10];
                float zz = zp[(size_t)(4 * u + 2) << 10];
                float zw = zp[(size_t)(4 * u + 3) << 10];
                acc += zx * ev.x;   // sequential fp32 FMA chain
                acc += zy * ev.y;   // (identical order to validated kernel)
                acc += zz * ev.z;
                acc += zw * ev.w;
            }
            float d = (zn - 2.0f * acc) + enb[code];
            unsigned long long q =
                (((unsigned long long)__float_as_uint(d)) << 32) | (unsigned)code;
            if (q < pk) pk = q;
        }
        unsigned long long q2 = __shfl_xor(pk, 1, 64);
        if (q2 < pk) pk = q2;
        if (side == 0) idx_out[row] = (int)(unsigned)(pk & 0xFFFFFFFFu);
    }
}

// ---------------- Overflow rows: block-per-row exact 512-code scan (≈never) ----------------
__global__ __launch_bounds__(256) void vq_rescore_of(const float* __restrict__ z,
                                                     const float* __restrict__ cb,
                                                     const float* __restrict__ enb,
                                                     const float* __restrict__ znb,
                                                     const unsigned* __restrict__ ctr,
                                                     const unsigned* __restrict__ oflist,
                                                     int* __restrict__ idx_out) {
    __shared__ unsigned long long best;
    const int t = threadIdx.x;
    unsigned n = ctr[1]; if (n > 4096u) n = 4096u;
    for (unsigned e = blockIdx.x; e < n; e += gridDim.x) {
        int row = (int)oflist[e];
        if (t == 0) best = 0xFFFFFFFFFFFFFFFFull;
        __syncthreads();
        const float* zp = z + (((size_t)(row >> 10)) << 18) + (row & 1023);
        const float  zn = znb[row];
        unsigned long long pk = 0xFFFFFFFFFFFFFFFFull;
#pragma unroll
        for (int h = 0; h < 2; ++h) {
            int code = (h << 8) + t;
            const float* ep = cb + ((size_t)code << 8);
            float acc = 0.f;
            for (int u = 0; u < 64; ++u) {
                float4 ev = *reinterpret_cast<const float4*>(ep + (u << 2));
                float zx = zp[(size_t)(4 * u + 0) << 10];
                float zy = zp[(size_t)(4 * u + 1) << 10];
                float zz = zp[(size_t)(4 * u + 2) << 10];
                float zw = zp[(size_t)(4 * u + 3) << 10];
                acc += zx * ev.x; acc += zy * ev.y;
                acc += zz * ev.z; acc += zw * ev.w;
            }
            float d = (zn - 2.0f * acc) + enb[code];
            unsigned long long q =
                (((unsigned long long)__float_as_uint(d)) << 32) | (unsigned)code;
            if (q < pk) pk = q;
        }
        atomicMin(&best, pk);
        __syncthreads();
        if (t == 0) idx_out[row] = (int)(unsigned)(best & 0xFFFFFFFFu);
        __syncthreads();
    }
}

// ---------------- Fallback exact argmin (validated round-2 kernel) ----------------
__global__ __launch_bounds__(512) void vq_argmin(const float* __restrict__ z,
                                                 const float* __restrict__ cb,
                                                 const float* __restrict__ enorm,
                                                 int* __restrict__ out_idx) {
    __shared__ float zs[64][SZ];
    __shared__ float es[64][SZ];
    __shared__ float ens[K_CODES];
    __shared__ float zn[64];
    __shared__ float red_d[64][32];
    __shared__ int   red_i[64][32];

    const int t  = threadIdx.x;
    const int r0 = blockIdx.x * 64;
    const int b  = r0 >> 10;
    const int n0 = r0 & 1023;
    const float* zb = z + (size_t)b * CDIM * HW;

#pragma unroll
    for (int p = 0; p < 8; ++p) {
        int lin = p * 512 + t;
        int c   = lin >> 4;
        int i0  = (lin & 15) << 2;
        float4 v = *reinterpret_cast<const float4*>(zb + (size_t)c * HW + n0 + i0);
        zs[i0 + 0][c] = v.x; zs[i0 + 1][c] = v.y;
        zs[i0 + 2][c] = v.z; zs[i0 + 3][c] = v.w;
    }
    if (t < K_CODES) ens[t] = enorm[t];
    __syncthreads();

    if (t < 64) {
        float s0 = 0.f, s1 = 0.f, s2 = 0.f, s3 = 0.f;
        for (int c = 0; c < CDIM; c += 4) {
            float4 v = *reinterpret_cast<const float4*>(&zs[t][c]);
            s0 += v.x * v.x; s1 += v.y * v.y; s2 += v.z * v.z; s3 += v.w * v.w;
        }
        zn[t] = (s0 + s1) + (s2 + s3);
    }

    const int ty = t >> 5, tx = t & 31, row0 = ty * 4;
    float best_d[4]; int best_i[4];
#pragma unroll
    for (int i = 0; i < 4; ++i) { best_d[i] = 3.4e38f; best_i[i] = 0; }

    for (int K0 = 0; K0 < K_CODES; K0 += 64) {
        __syncthreads();
#pragma unroll
        for (int p = 0; p < 8; ++p) {
            int lin = p * 512 + t;
            int j = lin >> 6, c4 = (lin & 63) << 2;
            *reinterpret_cast<float4*>(&es[j][c4]) =
                *reinterpret_cast<const float4*>(cb + (size_t)(K0 + j) * CDIM + c4);
        }
        __syncthreads();

        float acc[4][2];
#pragma unroll
        for (int i = 0; i < 4; ++i) { acc[i][0] = 0.f; acc[i][1] = 0.f; }
#pragma unroll 4
        for (int k = 0; k < CDIM; k += 4) {
            float4 a0 = *reinterpret_cast<const float4*>(&zs[row0 + 0][k]);
            float4 a1 = *reinterpret_cast<const float4*>(&zs[row0 + 1][k]);
            float4 a2 = *reinterpret_cast<const float4*>(&zs[row0 + 2][k]);
            float4 a3 = *reinterpret_cast<const float4*>(&zs[row0 + 3][k]);
            float4 e0 = *reinterpret_cast<const float4*>(&es[tx][k]);
            float4 e1 = *reinterpret_cast<const float4*>(&es[tx + 32][k]);
            float4 aa[4] = {a0, a1, a2, a3};
#pragma unroll
            for (int i = 0; i < 4; ++i) {
#pragma unroll
                for (int j = 0; j < 2; ++j) {
                    float4 e = j ? e1 : e0;
                    acc[i][j] += aa[i].x * e.x; acc[i][j] += aa[i].y * e.y;
                    acc[i][j] += aa[i].z * e.z; acc[i][j] += aa[i].w * e.w;
                }
            }
        }
#pragma unroll
        for (int i = 0; i < 4; ++i) {
            float zni = zn[row0 + i];
#pragma unroll
            for (int j = 0; j < 2; ++j) {
                int code = K0 + j * 32 + tx;
                float d = (zni - 2.0f * acc[i][j]) + ens[code];
                if (d < best_d[i]) { best_d[i] = d; best_i[i] = code; }
            }
        }
    }
    __syncthreads();
#pragma unroll
    for (int i = 0; i < 4; ++i) {
        red_d[row0 + i][tx] = best_d[i];
        red_i[row0 + i][tx] = best_i[i];
    }
    __syncthreads();
    if (t < 64) {
        float bd = red_d[t][0]; int bi = red_i[t][0];
        for (int x = 1; x < 32; ++x) {
            float d = red_d[t][x]; int ii = red_i[t][x];
            if (d < bd || (d == bd && ii < bi)) { bd = d; bi = ii; }
        }
        out_idx[r0 + t] = bi;
    }
}

// ---------------- Gather: float4 stores, 1024 blocks ----------------
__global__ __launch_bounds__(256) void vq_gather(const float* __restrict__ cb,
                                                 const int* __restrict__ idx,
                                                 float* __restrict__ out) {
    const int blk = blockIdx.x;
    const int b = blk >> 4;
    const int q = blk & 15;
    const int t = threadIdx.x;
    int4 cd = reinterpret_cast<const int4*>(idx + (b << 10))[t];
    if (q == 0) {
        float4 f = make_float4((float)cd.x, (float)cd.y, (float)cd.z, (float)cd.w);
        reinterpret_cast<float4*>(out + (size_t)NBATCH * CDIM * HW + ((size_t)b << 10))[t] = f;
    }
    const int c0 = q << 4;
    const float* e0 = cb + (size_t)cd.x * CDIM + c0;
    const float* e1 = cb + (size_t)cd.y * CDIM + c0;
    const float* e2 = cb + (size_t)cd.z * CDIM + c0;
    const float* e3 = cb + (size_t)cd.w * CDIM + c0;
    float* ob = out + ((size_t)b * CDIM + c0) * HW + (t << 2);
#pragma unroll 4
    for (int c = 0; c < 16; ++c) {
        float4 v = make_float4(e0[c], e1[c], e2[c], e3[c]);
        *reinterpret_cast<float4*>(ob) = v;
        ob += HW;
    }
}

extern "C" void kernel_launch(void* const* d_in, const int* in_sizes, int n_in,
                              void* d_out, int out_size, void* d_ws, size_t ws_size,
                              hipStream_t stream) {
    const float* z  = (const float*)d_in[0];
    const float* cb = (const float*)d_in[1];
    float* out = (float*)d_out;

    // ws layout
    int*            idx   = (int*)d_ws;                                  // 262144 B
    float*          en    = (float*)((char*)d_ws + 262144);              // 2048 B
    unsigned short* cb16  = (unsigned short*)((char*)d_ws + 264192);     // 262144 B
    float*          znb   = (float*)((char*)d_ws + 526336);              // 262144 B
    unsigned short* codes = (unsigned short*)((char*)d_ws + 788480);     // 2097152 B
    unsigned*       mlist = (unsigned*)((char*)d_ws + 2885632);          // 262144 B
    unsigned*       ctr   = (unsigned*)((char*)d_ws + 3147776);          // 16 B
    unsigned*       oflist= (unsigned*)((char*)d_ws + 3147792);          // 16384 B
    const size_t NEED_FULL = 3164176;

    if (ws_size >= NEED_FULL) {
        hipMemsetAsync(ctr, 0, 16, stream);
        vq_prep     <<<dim3(K_CODES), dim3(64),  0, stream>>>(cb, en, cb16);
        vq_zn       <<<dim3(1024),    dim3(256), 0, stream>>>(z, znb);
        vq_pass1    <<<dim3(512),     dim3(256), 0, stream>>>(z, cb16, codes, idx, mlist, oflist, ctr);
        vq_rescore2 <<<dim3(512),     dim3(256), 0, stream>>>(z, cb, en, znb, codes, ctr, mlist, idx);
        vq_rescore_of<<<dim3(64),     dim3(256), 0, stream>>>(z, cb, en, znb, ctr, oflist, idx);
    } else {
        vq_enorm  <<<dim3(K_CODES), dim3(64),  0, stream>>>(cb, en);
        vq_argmin <<<dim3(1024),    dim3(512), 0, stream>>>(z, cb, en, idx);
    }
    vq_gather<<<dim3(1024), dim3(256), 0, stream>>>(cb, idx, out);
}

// Round 8
// 225.123 us; speedup vs baseline: 1.0460x; 1.0460x over previous
//
#include <hip/hip_runtime.h>
#include <hip/hip_bf16.h>

#define K_CODES 512
#define CDIM    256
#define HW      1024
#define NBATCH  64
#define SZ      260   // validated LDS stride

typedef float  f32x16 __attribute__((ext_vector_type(16)));
typedef short  bf16x8 __attribute__((ext_vector_type(8)));

typedef __attribute__((address_space(1))) const unsigned int gld_src_t;
typedef __attribute__((address_space(3))) unsigned int       gld_dst_t;

__device__ __forceinline__ unsigned short f2bf(float x) {
    unsigned u = __float_as_uint(x);
    unsigned r = (u + 0x7FFFu + ((u >> 16) & 1u)) >> 16;   // RNE
    return (unsigned short)r;
}

// ---------------- Prep: en[512] fp32 + codebook bf16 ----------------
__global__ __launch_bounds__(64) void vq_prep(const float* __restrict__ cb,
                                              float* __restrict__ enorm,
                                              unsigned short* __restrict__ cb16) {
    int k = blockIdx.x;
    int l = threadIdx.x;
    float4 v = *reinterpret_cast<const float4*>(cb + (size_t)k * CDIM + l * 4);
    float s = (v.x * v.x + v.y * v.y) + (v.z * v.z + v.w * v.w);
#pragma unroll
    for (int off = 1; off < 64; off <<= 1) s += __shfl_xor(s, off, 64);
    if (l == 0) enorm[k] = s;
    ushort4 o;
    o.x = f2bf(v.x); o.y = f2bf(v.y); o.z = f2bf(v.z); o.w = f2bf(v.w);
    *reinterpret_cast<ushort4*>(cb16 + (size_t)k * CDIM + l * 4) = o;
}

__global__ __launch_bounds__(64) void vq_enorm(const float* __restrict__ cb,
                                               float* __restrict__ enorm) {
    int k = blockIdx.x;
    int l = threadIdx.x;
    float4 v = *reinterpret_cast<const float4*>(cb + (size_t)k * CDIM + l * 4);
    float s = (v.x * v.x + v.y * v.y) + (v.z * v.z + v.w * v.w);
#pragma unroll
    for (int off = 1; off < 64; off <<= 1) s += __shfl_xor(s, off, 64);
    if (l == 0) enorm[k] = s;
}

// ---------------- zn + zt: row norms (bit-identical) + transposed fp32 z ----------------
// zt lives in d_out's z_q region (64 MiB, fully overwritten by vq_gather later).
__global__ __launch_bounds__(256) void vq_zn(const float* __restrict__ z,
                                             float* __restrict__ zn_out,
                                             float* __restrict__ zt_out) {
    __shared__ float zs[64][SZ];
    const int t  = threadIdx.x;
    const int r0 = blockIdx.x * 64;
    const int b  = r0 >> 10;
    const int n0 = r0 & 1023;
    const float* zb = z + (size_t)b * CDIM * HW;

#pragma unroll
    for (int p = 0; p < 16; ++p) {
        int lin = p * 256 + t;
        int c   = lin >> 4;
        int i0  = (lin & 15) << 2;
        float4 v = *reinterpret_cast<const float4*>(zb + (size_t)c * HW + n0 + i0);
        zs[i0 + 0][c] = v.x; zs[i0 + 1][c] = v.y;
        zs[i0 + 2][c] = v.z; zs[i0 + 3][c] = v.w;
    }
    __syncthreads();
    if (t < 64) {
        float s0 = 0.f, s1 = 0.f, s2 = 0.f, s3 = 0.f;
        for (int c = 0; c < CDIM; c += 4) {
            float4 v = *reinterpret_cast<const float4*>(&zs[t][c]);
            s0 += v.x * v.x; s1 += v.y * v.y; s2 += v.z * v.z; s3 += v.w * v.w;
        }
        zn_out[r0 + t] = (s0 + s1) + (s2 + s3);
    }
    // write zt: 64 rows x 256 c, coalesced (wave w covers one row per step)
#pragma unroll
    for (int p = 0; p < 16; ++p) {
        int f   = p * 256 + t;          // float4 index
        int row = f >> 6;               // 0..63
        int c4  = (f & 63) << 2;        // 0..252
        float4 v = *reinterpret_cast<const float4*>(&zs[row][c4]);
        *reinterpret_cast<float4*>(zt_out + (((size_t)(r0 + row)) << 8) + c4) = v;
    }
}

// ---------------- Pass 1: single-sweep MFMA filter, reg top-6, async es pipeline ----------------
__global__ __launch_bounds__(256, 2) void vq_pass1(const float* __restrict__ z,
                                                   const unsigned short* __restrict__ cb16,
                                                   unsigned short* __restrict__ codes_out,
                                                   int* __restrict__ idx_out,
                                                   unsigned* __restrict__ mlist,
                                                   unsigned* __restrict__ oflist,
                                                   unsigned* __restrict__ ctr) {
    __shared__ __align__(16) char smem[70144];
    unsigned short* zs    = (unsigned short*)smem;            // 64KB transient
    unsigned*       zsw   = (unsigned*)smem;
    unsigned short* es    = (unsigned short*)smem;            // reuse: 4 x 16KB ring
    unsigned short* candl = (unsigned short*)(smem + 65536);  // 128*16 u16
    unsigned*       cntl  = (unsigned*)(smem + 69632);        // 128 u32

    const int t = threadIdx.x;
    const int l = t & 63, w = t >> 6;          // 4 waves
    const int r0 = blockIdx.x << 7;            // 128 rows/block
    const int b  = r0 >> 10, n0 = r0 & 1023;
    const float* zb = z + (size_t)b * (CDIM * HW);

    // ---- stage z: transpose + bf16 (identical bit-path to validated rounds)
#pragma unroll
    for (int p = 0; p < 16; ++p) {
        int lin = (p << 8) + t;
        int c2  = lin >> 5;          // 0..127 (k-pairs)
        int iq  = lin & 31;          // 0..31  (row-quads)
        const float* g0 = zb + (size_t)(2 * c2) * HW + n0 + (iq << 2);
        float4 a  = *reinterpret_cast<const float4*>(g0);
        float4 bb = *reinterpret_cast<const float4*>(g0 + HW);
        int up = (((c2 >> 2) ^ (iq & 7)) << 2) + (c2 & 3);
        const float* ap = &a.x; const float* bp = &bb.x;
#pragma unroll
        for (int j = 0; j < 4; ++j) {
            unsigned pk = (unsigned)f2bf(ap[j]) | ((unsigned)f2bf(bp[j]) << 16);
            zsw[((iq << 2) + j) * 128 + up] = pk;
        }
    }
    __syncthreads();

    // ---- B-frags (z rows) into registers (identical to validated rounds)
    const int lrow = l & 31, lh = l >> 5;
    const int lf  = (lrow >> 2) & 7;
    const int row = (w << 5) + lrow;           // 0..127
    bf16x8 zf[16];
#pragma unroll
    for (int s = 0; s < 16; ++s) {
        int u = (2 * s + lh) ^ lf;
        zf[s] = *reinterpret_cast<const bf16x8*>(&zs[row * 256 + (u << 3)]);
    }
    float sa = 0.f;
#pragma unroll
    for (int s = 0; s < 16; ++s)
#pragma unroll
        for (int j = 0; j < 8; ++j)
            sa += fabsf(__uint_as_float(((unsigned)(unsigned short)zf[s][j]) << 16));
    sa += __shfl_xor(sa, 32, 64);

    __syncthreads();   // all zs reads done -> es ring may reuse region

    // ---- async es stager: wave w fills chunks w*4..w*4+3 (1KB each) of a phase
    const int lq = l & 31, lhh = l >> 5;
    auto ISSUE = [&](int ph) {
#pragma unroll
        for (int j = 0; j < 4; ++j) {
            int chunk = (w << 2) + j;
            int lc    = (chunk << 1) + lhh;        // local code 0..31
            int su    = (lq - lc) & 31;            // pre-rotated source unit
            const unsigned short* gp = cb16 + (((size_t)((ph << 5) + lc)) << 8) + (su << 3);
            char* lp = smem + (((ph & 3) << 14) + (chunk << 10));
            __builtin_amdgcn_global_load_lds((gld_src_t*)gp, (gld_dst_t*)lp, 16, 0, 0);
        }
    };

    ISSUE(0); ISSUE(1);
    asm volatile("s_waitcnt vmcnt(4)" ::: "memory");
    __builtin_amdgcn_s_barrier();

    const float padf = sa * 1.7e-5f + 6.0e-4f;     // validated margin
    float runmax = -3.4e38f;
    float s0 = -3.4e38f, s1 = -3.4e38f, s2 = -3.4e38f,
          s3 = -3.4e38f, s4 = -3.4e38f, s5 = -3.4e38f;
    int   k0 = 0, k1 = 0, k2 = 0, k3 = 0, k4 = 0, k5 = 0;

    for (int p = 0; p < 16; ++p) {
        if (p + 2 < 16) ISSUE(p + 2);
        if (p >= 1) {
            if (p < 14)       asm volatile("s_waitcnt vmcnt(8)" ::: "memory");
            else if (p == 14) asm volatile("s_waitcnt vmcnt(4)" ::: "memory");
            else              asm volatile("s_waitcnt vmcnt(0)" ::: "memory");
            __builtin_amdgcn_s_barrier();
        }
        const unsigned short* eb = es + ((p & 3) << 13);

        f32x16 accA = {0.f,0.f,0.f,0.f,0.f,0.f,0.f,0.f,0.f,0.f,0.f,0.f,0.f,0.f,0.f,0.f};
        f32x16 accB = accA;
#pragma unroll
        for (int s = 0; s < 16; s += 2) {
            int u0 = (2 * s + lh + lrow) & 31;
            int u1 = (2 * s + 2 + lh + lrow) & 31;
            bf16x8 a0 = *reinterpret_cast<const bf16x8*>(&eb[(lrow << 8) + (u0 << 3)]);
            bf16x8 a1 = *reinterpret_cast<const bf16x8*>(&eb[(lrow << 8) + (u1 << 3)]);
            accA = __builtin_amdgcn_mfma_f32_32x32x16_bf16(a0, zf[s],     accA, 0, 0, 0);
            accB = __builtin_amdgcn_mfma_f32_32x32x16_bf16(a1, zf[s + 1], accB, 0, 0, 0);
        }

        float v[16]; float pm = -3.4e38f;
#pragma unroll
        for (int i = 0; i < 16; ++i) { v[i] = accA[i] + accB[i]; pm = fmaxf(pm, v[i]); }

        if (pm >= runmax - padf) {
            int cbase = (p << 5) + 4 * lh;
#pragma unroll
            for (int i = 0; i < 16; ++i) {
                float vv = v[i];
                int   cc = cbase + (i & 3) + 8 * (i >> 2);
                bool c5 = vv > s5, c4 = vv > s4, c3 = vv > s3,
                     c2 = vv > s2, c1 = vv > s1, c0 = vv > s0;
                s5 = c5 ? (c4 ? s4 : vv) : s5;  k5 = c5 ? (c4 ? k4 : cc) : k5;
                s4 = c4 ? (c3 ? s3 : vv) : s4;  k4 = c4 ? (c3 ? k3 : cc) : k4;
                s3 = c3 ? (c2 ? s2 : vv) : s3;  k3 = c3 ? (c2 ? k2 : cc) : k3;
                s2 = c2 ? (c1 ? s1 : vv) : s2;  k2 = c2 ? (c1 ? k1 : cc) : k2;
                s1 = c1 ? (c0 ? s0 : vv) : s1;  k1 = c1 ? (c0 ? k0 : cc) : k1;
                s0 = c0 ? vv : s0;              k0 = c0 ? cc : k0;
            }
        }
        runmax = fmaxf(runmax, pm);
    }

    // ---- extraction: merge lane pair (lh 0/1), filter by final threshold
    float rowmax = fmaxf(runmax, __shfl_xor(runmax, 32, 64));
    const float thr = rowmax - padf;
    float p0 = __shfl_xor(s0, 32, 64), p1 = __shfl_xor(s1, 32, 64),
          p2 = __shfl_xor(s2, 32, 64), p3 = __shfl_xor(s3, 32, 64),
          p4 = __shfl_xor(s4, 32, 64), p5 = __shfl_xor(s5, 32, 64);
    int   q0 = __shfl_xor(k0, 32, 64), q1 = __shfl_xor(k1, 32, 64),
          q2 = __shfl_xor(k2, 32, 64), q3 = __shfl_xor(k3, 32, 64),
          q4 = __shfl_xor(k4, 32, 64), q5 = __shfl_xor(k5, 32, 64);

    if (lh == 0) {
        int cnt = 0;
#define VQ_EMIT(SV, KV) do { if ((SV) >= thr) { candl[(row << 4) + cnt] = (unsigned short)(KV); ++cnt; } } while (0)
        VQ_EMIT(s0, k0); VQ_EMIT(s1, k1); VQ_EMIT(s2, k2);
        VQ_EMIT(s3, k3); VQ_EMIT(s4, k4); VQ_EMIT(s5, k5);
        VQ_EMIT(p0, q0); VQ_EMIT(p1, q1); VQ_EMIT(p2, q2);
        VQ_EMIT(p3, q3); VQ_EMIT(p4, q4); VQ_EMIT(p5, q5);
#undef VQ_EMIT
        bool of = (s5 >= thr) || (p5 >= thr);   // possible 7th candidate in a half
        cntl[row] = of ? 17u : (unsigned)cnt;
    }
    __syncthreads();

    if (t < 128) {
        unsigned c = cntl[t];
        if (c == 1u) idx_out[r0 + t] = (int)candl[t << 4];
        bool multi = (c >= 2u && c <= 16u);
        bool ofl   = (c > 16u);
        unsigned long long m = __ballot(multi);
        int lane = t & 63;
        int rank = __popcll(m & ((1ull << lane) - 1ull));
        int tot  = __popcll(m);
        unsigned base = 0;
        if (lane == 0 && tot) base = atomicAdd(&ctr[0], (unsigned)tot);
        base = __shfl(base, 0, 64);
        if (multi) mlist[base + rank] = (unsigned)(r0 + t) | (c << 16);
        if (ofl) {
            unsigned pos = atomicAdd(&ctr[1], 1u);
            if (pos < 65536u) oflist[pos] = (unsigned)(r0 + t);
        }
    }
    reinterpret_cast<uint4*>(codes_out + ((size_t)r0 << 4))[t] =
        reinterpret_cast<const uint4*>(candl)[t];
}

// ---------------- Pass 2: exact fp32 rescore via contiguous zt rows ----------------
__global__ __launch_bounds__(256) void vq_rescore2(const float* __restrict__ zt,
                                                   const float* __restrict__ cb,
                                                   const float* __restrict__ enb,
                                                   const float* __restrict__ znb,
                                                   const unsigned short* __restrict__ codes_in,
                                                   const unsigned* __restrict__ ctr,
                                                   const unsigned* __restrict__ mlist,
                                                   int* __restrict__ idx_out) {
    const unsigned N = ctr[0];
    const unsigned total = N * 2u;
    unsigned i = blockIdx.x * 256u + threadIdx.x;
    for (; i < total; i += gridDim.x * 256u) {
        unsigned e   = mlist[i >> 1];
        int side     = (int)(i & 1u);
        int row      = (int)(e & 0xFFFFu);
        int cnt      = (int)(e >> 16);
        const float* zp = zt + ((size_t)row << 8);
        const float  zn = znb[row];
        unsigned long long pk = 0xFFFFFFFFFFFFFFFFull;

        for (int j = side; j < cnt; j += 2) {
            int code = (int)codes_in[((size_t)row << 4) + j];
            const float* ep = cb + ((size_t)code << 8);
            float acc = 0.f;
#pragma unroll 8
            for (int u = 0; u < 64; ++u) {
                float4 zv = *reinterpret_cast<const float4*>(zp + (u << 2));
                float4 ev = *reinterpret_cast<const float4*>(ep + (u << 2));
                acc += zv.x * ev.x;   // sequential fp32 FMA chain
                acc += zv.y * ev.y;   // (identical order to validated kernel)
                acc += zv.z * ev.z;
                acc += zv.w * ev.w;
            }
            float d = (zn - 2.0f * acc) + enb[code];
            unsigned long long q =
                (((unsigned long long)__float_as_uint(d)) << 32) | (unsigned)code;
            if (q < pk) pk = q;
        }
        unsigned long long q2 = __shfl_xor(pk, 1, 64);
        if (q2 < pk) pk = q2;
        if (side == 0) idx_out[row] = (int)(unsigned)(pk & 0xFFFFFFFFu);
    }
}

// ---------------- Overflow rows: one WAVE per row, 8 codes/lane ILP ----------------
__global__ __launch_bounds__(256) void vq_rescore_of(const float* __restrict__ zt,
                                                     const float* __restrict__ cb,
                                                     const float* __restrict__ enb,
                                                     const float* __restrict__ znb,
                                                     const unsigned* __restrict__ ctr,
                                                     const unsigned* __restrict__ oflist,
                                                     int* __restrict__ idx_out) {
    unsigned n = ctr[1]; if (n > 65536u) n = 65536u;
    const unsigned wv = (blockIdx.x << 2) + (threadIdx.x >> 6);
    const unsigned nw = gridDim.x << 2;
    const int l = threadIdx.x & 63;
    for (unsigned e = wv; e < n; e += nw) {
        int row = (int)oflist[e];
        const float* zp = zt + ((size_t)row << 8);
        const float  zn = znb[row];
        const float* ep = cb + ((size_t)l << 8);   // codes l, l+64, ..., l+448
        float acc[8];
#pragma unroll
        for (int q = 0; q < 8; ++q) acc[q] = 0.f;
        for (int u = 0; u < 64; ++u) {
            float4 zv = *reinterpret_cast<const float4*>(zp + (u << 2));
#pragma unroll
            for (int q = 0; q < 8; ++q) {
                float4 ev = *reinterpret_cast<const float4*>(ep + ((size_t)q << 14) + (u << 2));
                acc[q] += zv.x * ev.x; acc[q] += zv.y * ev.y;   // identical chain order
                acc[q] += zv.z * ev.z; acc[q] += zv.w * ev.w;
            }
        }
        unsigned long long pk = 0xFFFFFFFFFFFFFFFFull;
#pragma unroll
        for (int q = 0; q < 8; ++q) {
            int code = (q << 6) + l;
            float d = (zn - 2.0f * acc[q]) + enb[code];
            unsigned long long pp =
                (((unsigned long long)__float_as_uint(d)) << 32) | (unsigned)code;
            if (pp < pk) pk = pp;
        }
#pragma unroll
        for (int o = 1; o < 64; o <<= 1) {
            unsigned long long q2 = __shfl_xor(pk, o, 64);
            if (q2 < pk) pk = q2;
        }
        if (l == 0) idx_out[row] = (int)(unsigned)(pk & 0xFFFFFFFFu);
    }
}

// ---------------- Fallback exact argmin (validated round-2 kernel) ----------------
__global__ __launch_bounds__(512) void vq_argmin(const float* __restrict__ z,
                                                 const float* __restrict__ cb,
                                                 const float* __restrict__ enorm,
                                                 int* __restrict__ out_idx) {
    __shared__ float zs[64][SZ];
    __shared__ float es[64][SZ];
    __shared__ float ens[K_CODES];
    __shared__ float zn[64];
    __shared__ float red_d[64][32];
    __shared__ int   red_i[64][32];

    const int t  = threadIdx.x;
    const int r0 = blockIdx.x * 64;
    const int b  = r0 >> 10;
    const int n0 = r0 & 1023;
    const float* zb = z + (size_t)b * CDIM * HW;

#pragma unroll
    for (int p = 0; p < 8; ++p) {
        int lin = p * 512 + t;
        int c   = lin >> 4;
        int i0  = (lin & 15) << 2;
        float4 v = *reinterpret_cast<const float4*>(zb + (size_t)c * HW + n0 + i0);
        zs[i0 + 0][c] = v.x; zs[i0 + 1][c] = v.y;
        zs[i0 + 2][c] = v.z; zs[i0 + 3][c] = v.w;
    }
    if (t < K_CODES) ens[t] = enorm[t];
    __syncthreads();

    if (t < 64) {
        float s0 = 0.f, s1 = 0.f, s2 = 0.f, s3 = 0.f;
        for (int c = 0; c < CDIM; c += 4) {
            float4 v = *reinterpret_cast<const float4*>(&zs[t][c]);
            s0 += v.x * v.x; s1 += v.y * v.y; s2 += v.z * v.z; s3 += v.w * v.w;
        }
        zn[t] = (s0 + s1) + (s2 + s3);
    }

    const int ty = t >> 5, tx = t & 31, row0 = ty * 4;
    float best_d[4]; int best_i[4];
#pragma unroll
    for (int i = 0; i < 4; ++i) { best_d[i] = 3.4e38f; best_i[i] = 0; }

    for (int K0 = 0; K0 < K_CODES; K0 += 64) {
        __syncthreads();
#pragma unroll
        for (int p = 0; p < 8; ++p) {
            int lin = p * 512 + t;
            int j = lin >> 6, c4 = (lin & 63) << 2;
            *reinterpret_cast<float4*>(&es[j][c4]) =
                *reinterpret_cast<const float4*>(cb + (size_t)(K0 + j) * CDIM + c4);
        }
        __syncthreads();

        float acc[4][2];
#pragma unroll
        for (int i = 0; i < 4; ++i) { acc[i][0] = 0.f; acc[i][1] = 0.f; }
#pragma unroll 4
        for (int k = 0; k < CDIM; k += 4) {
            float4 a0 = *reinterpret_cast<const float4*>(&zs[row0 + 0][k]);
            float4 a1 = *reinterpret_cast<const float4*>(&zs[row0 + 1][k]);
            float4 a2 = *reinterpret_cast<const float4*>(&zs[row0 + 2][k]);
            float4 a3 = *reinterpret_cast<const float4*>(&zs[row0 + 3][k]);
            float4 e0 = *reinterpret_cast<const float4*>(&es[tx][k]);
            float4 e1 = *reinterpret_cast<const float4*>(&es[tx + 32][k]);
            float4 aa[4] = {a0, a1, a2, a3};
#pragma unroll
            for (int i = 0; i < 4; ++i) {
#pragma unroll
                for (int j = 0; j < 2; ++j) {
                    float4 e = j ? e1 : e0;
                    acc[i][j] += aa[i].x * e.x; acc[i][j] += aa[i].y * e.y;
                    acc[i][j] += aa[i].z * e.z; acc[i][j] += aa[i].w * e.w;
                }
            }
        }
#pragma unroll
        for (int i = 0; i < 4; ++i) {
            float zni = zn[row0 + i];
#pragma unroll
            for (int j = 0; j < 2; ++j) {
                int code = K0 + j * 32 + tx;
                float d = (zni - 2.0f * acc[i][j]) + ens[code];
                if (d < best_d[i]) { best_d[i] = d; best_i[i] = code; }
            }
        }
    }
    __syncthreads();
#pragma unroll
    for (int i = 0; i < 4; ++i) {
        red_d[row0 + i][tx] = best_d[i];
        red_i[row0 + i][tx] = best_i[i];
    }
    __syncthreads();
    if (t < 64) {
        float bd = red_d[t][0]; int bi = red_i[t][0];
        for (int x = 1; x < 32; ++x) {
            float d = red_d[t][x]; int ii = red_i[t][x];
            if (d < bd || (d == bd && ii < bi)) { bd = d; bi = ii; }
        }
        out_idx[r0 + t] = bi;
    }
}

// ---------------- Gather: float4 stores, 1024 blocks ----------------
__global__ __launch_bounds__(256) void vq_gather(const float* __restrict__ cb,
                                                 const int* __restrict__ idx,
                                                 float* __restrict__ out) {
    const int blk = blockIdx.x;
    const int b = blk >> 4;
    const int q = blk & 15;
    const int t = threadIdx.x;
    int4 cd = reinterpret_cast<const int4*>(idx + (b << 10))[t];
    if (q == 0) {
        float4 f = make_float4((float)cd.x, (float)cd.y, (float)cd.z, (float)cd.w);
        reinterpret_cast<float4*>(out + (size_t)NBATCH * CDIM * HW + ((size_t)b << 10))[t] = f;
    }
    const int c0 = q << 4;
    const float* e0 = cb + (size_t)cd.x * CDIM + c0;
    const float* e1 = cb + (size_t)cd.y * CDIM + c0;
    const float* e2 = cb + (size_t)cd.z * CDIM + c0;
    const float* e3 = cb + (size_t)cd.w * CDIM + c0;
    float* ob = out + ((size_t)b * CDIM + c0) * HW + (t << 2);
#pragma unroll 4
    for (int c = 0; c < 16; ++c) {
        float4 v = make_float4(e0[c], e1[c], e2[c], e3[c]);
        *reinterpret_cast<float4*>(ob) = v;
        ob += HW;
    }
}

extern "C" void kernel_launch(void* const* d_in, const int* in_sizes, int n_in,
                              void* d_out, int out_size, void* d_ws, size_t ws_size,
                              hipStream_t stream) {
    const float* z  = (const float*)d_in[0];
    const float* cb = (const float*)d_in[1];
    float* out = (float*)d_out;
    float* zt  = (float*)d_out;   // z_q region (exactly 64 MiB) used as scratch, overwritten by gather

    // ws layout
    int*            idx   = (int*)d_ws;                                  // 262144 B
    float*          en    = (float*)((char*)d_ws + 262144);              // 2048 B
    unsigned short* cb16  = (unsigned short*)((char*)d_ws + 264192);     // 262144 B
    float*          znb   = (float*)((char*)d_ws + 526336);              // 262144 B
    unsigned short* codes = (unsigned short*)((char*)d_ws + 788480);     // 2097152 B
    unsigned*       mlist = (unsigned*)((char*)d_ws + 2885632);          // 262144 B
    unsigned*       ctr   = (unsigned*)((char*)d_ws + 3147776);          // 16 B
    unsigned*       oflist= (unsigned*)((char*)d_ws + 3147792);          // 262144 B
    const size_t NEED_FULL = 3409936;

    if (ws_size >= NEED_FULL) {
        hipMemsetAsync(ctr, 0, 16, stream);
        vq_prep      <<<dim3(K_CODES), dim3(64),  0, stream>>>(cb, en, cb16);
        vq_zn        <<<dim3(1024),    dim3(256), 0, stream>>>(z, znb, zt);
        vq_pass1     <<<dim3(512),     dim3(256), 0, stream>>>(z, cb16, codes, idx, mlist, oflist, ctr);
        vq_rescore2  <<<dim3(2048),    dim3(256), 0, stream>>>(zt, cb, en, znb, codes, ctr, mlist, idx);
        vq_rescore_of<<<dim3(256),     dim3(256), 0, stream>>>(zt, cb, en, znb, ctr, oflist, idx);
    } else {
        vq_enorm  <<<dim3(K_CODES), dim3(64),  0, stream>>>(cb, en);
        vq_argmin <<<dim3(1024),    dim3(512), 0, stream>>>(z, cb, en, idx);
    }
    vq_gather<<<dim3(1024), dim3(256), 0, stream>>>(cb, idx, out);
}

// Round 9
// 177.697 us; speedup vs baseline: 1.3252x; 1.2669x over previous
//
#include <hip/hip_runtime.h>
#include <hip/hip_bf16.h>

#define K_CODES 512
#define CDIM    256
#define HW      1024
#define NBATCH  64
#define SZ      260   // validated LDS stride

typedef float  f32x16 __attribute__((ext_vector_type(16)));
typedef short  bf16x8 __attribute__((ext_vector_type(8)));

typedef __attribute__((address_space(1))) const unsigned int gld_src_t;
typedef __attribute__((address_space(3))) unsigned int       gld_dst_t;

__device__ __forceinline__ unsigned short f2bf(float x) {
    unsigned u = __float_as_uint(x);
    unsigned r = (u + 0x7FFFu + ((u >> 16) & 1u)) >> 16;   // RNE
    return (unsigned short)r;
}

// ---------------- Prep: en[512] fp32 + codebook bf16 ----------------
__global__ __launch_bounds__(64) void vq_prep(const float* __restrict__ cb,
                                              float* __restrict__ enorm,
                                              unsigned short* __restrict__ cb16) {
    int k = blockIdx.x;
    int l = threadIdx.x;
    float4 v = *reinterpret_cast<const float4*>(cb + (size_t)k * CDIM + l * 4);
    float s = (v.x * v.x + v.y * v.y) + (v.z * v.z + v.w * v.w);
#pragma unroll
    for (int off = 1; off < 64; off <<= 1) s += __shfl_xor(s, off, 64);
    if (l == 0) enorm[k] = s;
    ushort4 o;
    o.x = f2bf(v.x); o.y = f2bf(v.y); o.z = f2bf(v.z); o.w = f2bf(v.w);
    *reinterpret_cast<ushort4*>(cb16 + (size_t)k * CDIM + l * 4) = o;
}

__global__ __launch_bounds__(64) void vq_enorm(const float* __restrict__ cb,
                                               float* __restrict__ enorm) {
    int k = blockIdx.x;
    int l = threadIdx.x;
    float4 v = *reinterpret_cast<const float4*>(cb + (size_t)k * CDIM + l * 4);
    float s = (v.x * v.x + v.y * v.y) + (v.z * v.z + v.w * v.w);
#pragma unroll
    for (int off = 1; off < 64; off <<= 1) s += __shfl_xor(s, off, 64);
    if (l == 0) enorm[k] = s;
}

// ---------------- cbT: transpose codebook to [c][code] for coalesced column reads ----------------
// 32 blocks (8 k-tiles x 4 c-tiles), 256 thr, 64x64 LDS tile (+1 pad).
__global__ __launch_bounds__(256) void vq_cbt(const float* __restrict__ cb,
                                              float* __restrict__ cbT) {
    __shared__ float st[64][65];
    const int t  = threadIdx.x;
    const int k0 = (blockIdx.x >> 2) << 6;
    const int c0 = (blockIdx.x & 3) << 6;
#pragma unroll
    for (int q = 0; q < 4; ++q) {
        int lin = (q << 8) + t;
        int kr  = lin >> 4;            // 0..63
        int cc  = (lin & 15) << 2;     // 0..60
        float4 v = *reinterpret_cast<const float4*>(cb + (size_t)(k0 + kr) * CDIM + c0 + cc);
        st[kr][cc + 0] = v.x; st[kr][cc + 1] = v.y;
        st[kr][cc + 2] = v.z; st[kr][cc + 3] = v.w;
    }
    __syncthreads();
#pragma unroll
    for (int q = 0; q < 4; ++q) {
        int lin = (q << 8) + t;
        int cr  = lin >> 4;            // 0..63
        int kk  = (lin & 15) << 2;     // 0..60
        float4 v = make_float4(st[kk + 0][cr], st[kk + 1][cr],
                               st[kk + 2][cr], st[kk + 3][cr]);
        *reinterpret_cast<float4*>(cbT + (size_t)(c0 + cr) * K_CODES + k0 + kk) = v;
    }
}

// ---------------- zn + zt: row norms (bit-identical) + transposed fp32 z ----------------
// zt lives in d_out's z_q region (64 MiB, fully overwritten by vq_gather later).
__global__ __launch_bounds__(256) void vq_zn(const float* __restrict__ z,
                                             float* __restrict__ zn_out,
                                             float* __restrict__ zt_out) {
    __shared__ float zs[64][SZ];
    const int t  = threadIdx.x;
    const int r0 = blockIdx.x * 64;
    const int b  = r0 >> 10;
    const int n0 = r0 & 1023;
    const float* zb = z + (size_t)b * CDIM * HW;

#pragma unroll
    for (int p = 0; p < 16; ++p) {
        int lin = p * 256 + t;
        int c   = lin >> 4;
        int i0  = (lin & 15) << 2;
        float4 v = *reinterpret_cast<const float4*>(zb + (size_t)c * HW + n0 + i0);
        zs[i0 + 0][c] = v.x; zs[i0 + 1][c] = v.y;
        zs[i0 + 2][c] = v.z; zs[i0 + 3][c] = v.w;
    }
    __syncthreads();
    if (t < 64) {
        float s0 = 0.f, s1 = 0.f, s2 = 0.f, s3 = 0.f;
        for (int c = 0; c < CDIM; c += 4) {
            float4 v = *reinterpret_cast<const float4*>(&zs[t][c]);
            s0 += v.x * v.x; s1 += v.y * v.y; s2 += v.z * v.z; s3 += v.w * v.w;
        }
        zn_out[r0 + t] = (s0 + s1) + (s2 + s3);
    }
#pragma unroll
    for (int p = 0; p < 16; ++p) {
        int f   = p * 256 + t;
        int row = f >> 6;
        int c4  = (f & 63) << 2;
        float4 v = *reinterpret_cast<const float4*>(&zs[row][c4]);
        *reinterpret_cast<float4*>(zt_out + (((size_t)(r0 + row)) << 8) + c4) = v;
    }
}

// ---------------- Pass 1: single-sweep MFMA filter, reg top-6, async es pipeline ----------------
__global__ __launch_bounds__(256, 2) void vq_pass1(const float* __restrict__ z,
                                                   const unsigned short* __restrict__ cb16,
                                                   unsigned short* __restrict__ codes_out,
                                                   int* __restrict__ idx_out,
                                                   unsigned* __restrict__ mlist,
                                                   unsigned* __restrict__ oflist,
                                                   unsigned* __restrict__ ctr) {
    __shared__ __align__(16) char smem[70144];
    unsigned short* zs    = (unsigned short*)smem;            // 64KB transient
    unsigned*       zsw   = (unsigned*)smem;
    unsigned short* es    = (unsigned short*)smem;            // reuse: 4 x 16KB ring
    unsigned short* candl = (unsigned short*)(smem + 65536);  // 128*16 u16
    unsigned*       cntl  = (unsigned*)(smem + 69632);        // 128 u32

    const int t = threadIdx.x;
    const int l = t & 63, w = t >> 6;          // 4 waves
    const int r0 = blockIdx.x << 7;            // 128 rows/block
    const int b  = r0 >> 10, n0 = r0 & 1023;
    const float* zb = z + (size_t)b * (CDIM * HW);

    // ---- stage z: transpose + bf16 (identical bit-path to validated rounds)
#pragma unroll
    for (int p = 0; p < 16; ++p) {
        int lin = (p << 8) + t;
        int c2  = lin >> 5;          // 0..127 (k-pairs)
        int iq  = lin & 31;          // 0..31  (row-quads)
        const float* g0 = zb + (size_t)(2 * c2) * HW + n0 + (iq << 2);
        float4 a  = *reinterpret_cast<const float4*>(g0);
        float4 bb = *reinterpret_cast<const float4*>(g0 + HW);
        int up = (((c2 >> 2) ^ (iq & 7)) << 2) + (c2 & 3);
        const float* ap = &a.x; const float* bp = &bb.x;
#pragma unroll
        for (int j = 0; j < 4; ++j) {
            unsigned pk = (unsigned)f2bf(ap[j]) | ((unsigned)f2bf(bp[j]) << 16);
            zsw[((iq << 2) + j) * 128 + up] = pk;
        }
    }
    __syncthreads();

    // ---- B-frags (z rows) into registers (identical to validated rounds)
    const int lrow = l & 31, lh = l >> 5;
    const int lf  = (lrow >> 2) & 7;
    const int row = (w << 5) + lrow;           // 0..127
    bf16x8 zf[16];
#pragma unroll
    for (int s = 0; s < 16; ++s) {
        int u = (2 * s + lh) ^ lf;
        zf[s] = *reinterpret_cast<const bf16x8*>(&zs[row * 256 + (u << 3)]);
    }
    float sa = 0.f;
#pragma unroll
    for (int s = 0; s < 16; ++s)
#pragma unroll
        for (int j = 0; j < 8; ++j)
            sa += fabsf(__uint_as_float(((unsigned)(unsigned short)zf[s][j]) << 16));
    sa += __shfl_xor(sa, 32, 64);

    __syncthreads();   // all zs reads done -> es ring may reuse region

    // ---- async es stager: wave w fills chunks w*4..w*4+3 (1KB each) of a phase
    const int lq = l & 31, lhh = l >> 5;
    auto ISSUE = [&](int ph) {
#pragma unroll
        for (int j = 0; j < 4; ++j) {
            int chunk = (w << 2) + j;
            int lc    = (chunk << 1) + lhh;        // local code 0..31
            int su    = (lq - lc) & 31;            // pre-rotated source unit
            const unsigned short* gp = cb16 + (((size_t)((ph << 5) + lc)) << 8) + (su << 3);
            char* lp = smem + (((ph & 3) << 14) + (chunk << 10));
            __builtin_amdgcn_global_load_lds((gld_src_t*)gp, (gld_dst_t*)lp, 16, 0, 0);
        }
    };

    ISSUE(0); ISSUE(1);
    asm volatile("s_waitcnt vmcnt(4)" ::: "memory");
    __builtin_amdgcn_s_barrier();

    const float padf = sa * 1.7e-5f + 6.0e-4f;     // validated margin
    float runmax = -3.4e38f;
    float s0 = -3.4e38f, s1 = -3.4e38f, s2 = -3.4e38f,
          s3 = -3.4e38f, s4 = -3.4e38f, s5 = -3.4e38f;
    int   k0 = 0, k1 = 0, k2 = 0, k3 = 0, k4 = 0, k5 = 0;

    for (int p = 0; p < 16; ++p) {
        if (p + 2 < 16) ISSUE(p + 2);
        if (p >= 1) {
            if (p < 14)       asm volatile("s_waitcnt vmcnt(8)" ::: "memory");
            else if (p == 14) asm volatile("s_waitcnt vmcnt(4)" ::: "memory");
            else              asm volatile("s_waitcnt vmcnt(0)" ::: "memory");
            __builtin_amdgcn_s_barrier();
        }
        const unsigned short* eb = es + ((p & 3) << 13);

        f32x16 accA = {0.f,0.f,0.f,0.f,0.f,0.f,0.f,0.f,0.f,0.f,0.f,0.f,0.f,0.f,0.f,0.f};
        f32x16 accB = accA;
#pragma unroll
        for (int s = 0; s < 16; s += 2) {
            int u0 = (2 * s + lh + lrow) & 31;
            int u1 = (2 * s + 2 + lh + lrow) & 31;
            bf16x8 a0 = *reinterpret_cast<const bf16x8*>(&eb[(lrow << 8) + (u0 << 3)]);
            bf16x8 a1 = *reinterpret_cast<const bf16x8*>(&eb[(lrow << 8) + (u1 << 3)]);
            accA = __builtin_amdgcn_mfma_f32_32x32x16_bf16(a0, zf[s],     accA, 0, 0, 0);
            accB = __builtin_amdgcn_mfma_f32_32x32x16_bf16(a1, zf[s + 1], accB, 0, 0, 0);
        }

        float v[16]; float pm = -3.4e38f;
#pragma unroll
        for (int i = 0; i < 16; ++i) { v[i] = accA[i] + accB[i]; pm = fmaxf(pm, v[i]); }

        if (pm >= runmax - padf) {
            int cbase = (p << 5) + 4 * lh;
#pragma unroll
            for (int i = 0; i < 16; ++i) {
                float vv = v[i];
                int   cc = cbase + (i & 3) + 8 * (i >> 2);
                bool c5 = vv > s5, c4 = vv > s4, c3 = vv > s3,
                     c2 = vv > s2, c1 = vv > s1, c0 = vv > s0;
                s5 = c5 ? (c4 ? s4 : vv) : s5;  k5 = c5 ? (c4 ? k4 : cc) : k5;
                s4 = c4 ? (c3 ? s3 : vv) : s4;  k4 = c4 ? (c3 ? k3 : cc) : k4;
                s3 = c3 ? (c2 ? s2 : vv) : s3;  k3 = c3 ? (c2 ? k2 : cc) : k3;
                s2 = c2 ? (c1 ? s1 : vv) : s2;  k2 = c2 ? (c1 ? k1 : cc) : k2;
                s1 = c1 ? (c0 ? s0 : vv) : s1;  k1 = c1 ? (c0 ? k0 : cc) : k1;
                s0 = c0 ? vv : s0;              k0 = c0 ? cc : k0;
            }
        }
        runmax = fmaxf(runmax, pm);
    }

    // ---- extraction: merge lane pair (lh 0/1), filter by final threshold
    float rowmax = fmaxf(runmax, __shfl_xor(runmax, 32, 64));
    const float thr = rowmax - padf;
    float p0 = __shfl_xor(s0, 32, 64), p1 = __shfl_xor(s1, 32, 64),
          p2 = __shfl_xor(s2, 32, 64), p3 = __shfl_xor(s3, 32, 64),
          p4 = __shfl_xor(s4, 32, 64), p5 = __shfl_xor(s5, 32, 64);
    int   q0 = __shfl_xor(k0, 32, 64), q1 = __shfl_xor(k1, 32, 64),
          q2 = __shfl_xor(k2, 32, 64), q3 = __shfl_xor(k3, 32, 64),
          q4 = __shfl_xor(k4, 32, 64), q5 = __shfl_xor(k5, 32, 64);

    if (lh == 0) {
        int cnt = 0;
#define VQ_EMIT(SV, KV) do { if ((SV) >= thr) { candl[(row << 4) + cnt] = (unsigned short)(KV); ++cnt; } } while (0)
        VQ_EMIT(s0, k0); VQ_EMIT(s1, k1); VQ_EMIT(s2, k2);
        VQ_EMIT(s3, k3); VQ_EMIT(s4, k4); VQ_EMIT(s5, k5);
        VQ_EMIT(p0, q0); VQ_EMIT(p1, q1); VQ_EMIT(p2, q2);
        VQ_EMIT(p3, q3); VQ_EMIT(p4, q4); VQ_EMIT(p5, q5);
#undef VQ_EMIT
        bool of = (s5 >= thr) || (p5 >= thr);   // possible 7th candidate in a half
        cntl[row] = of ? 17u : (unsigned)cnt;
    }
    __syncthreads();

    if (t < 128) {
        unsigned c = cntl[t];
        if (c == 1u) idx_out[r0 + t] = (int)candl[t << 4];
        bool multi = (c >= 2u && c <= 16u);
        bool ofl   = (c > 16u);
        unsigned long long m = __ballot(multi);
        int lane = t & 63;
        int rank = __popcll(m & ((1ull << lane) - 1ull));
        int tot  = __popcll(m);
        unsigned base = 0;
        if (lane == 0 && tot) base = atomicAdd(&ctr[0], (unsigned)tot);
        base = __shfl(base, 0, 64);
        if (multi) mlist[base + rank] = (unsigned)(r0 + t) | (c << 16);
        if (ofl) {
            unsigned pos = atomicAdd(&ctr[1], 1u);
            if (pos < 65536u) oflist[pos] = (unsigned)(r0 + t);
        }
    }
    reinterpret_cast<uint4*>(codes_out + ((size_t)r0 << 4))[t] =
        reinterpret_cast<const uint4*>(candl)[t];
}

// ---------------- Pass 2: exact fp32 rescore via contiguous zt rows ----------------
__global__ __launch_bounds__(256) void vq_rescore2(const float* __restrict__ zt,
                                                   const float* __restrict__ cb,
                                                   const float* __restrict__ enb,
                                                   const float* __restrict__ znb,
                                                   const unsigned short* __restrict__ codes_in,
                                                   const unsigned* __restrict__ ctr,
                                                   const unsigned* __restrict__ mlist,
                                                   int* __restrict__ idx_out) {
    const unsigned N = ctr[0];
    const unsigned total = N * 2u;
    unsigned i = blockIdx.x * 256u + threadIdx.x;
    for (; i < total; i += gridDim.x * 256u) {
        unsigned e   = mlist[i >> 1];
        int side     = (int)(i & 1u);
        int row      = (int)(e & 0xFFFFu);
        int cnt      = (int)(e >> 16);
        const float* zp = zt + ((size_t)row << 8);
        const float  zn = znb[row];
        unsigned long long pk = 0xFFFFFFFFFFFFFFFFull;

        for (int j = side; j < cnt; j += 2) {
            int code = (int)codes_in[((size_t)row << 4) + j];
            const float* ep = cb + ((size_t)code << 8);
            float acc = 0.f;
#pragma unroll 8
            for (int u = 0; u < 64; ++u) {
                float4 zv = *reinterpret_cast<const float4*>(zp + (u << 2));
                float4 ev = *reinterpret_cast<const float4*>(ep + (u << 2));
                acc += zv.x * ev.x;   // sequential fp32 FMA chain
                acc += zv.y * ev.y;   // (identical order to validated kernel)
                acc += zv.z * ev.z;
                acc += zv.w * ev.w;
            }
            float d = (zn - 2.0f * acc) + enb[code];
            unsigned long long q =
                (((unsigned long long)__float_as_uint(d)) << 32) | (unsigned)code;
            if (q < pk) pk = q;
        }
        unsigned long long q2 = __shfl_xor(pk, 1, 64);
        if (q2 < pk) pk = q2;
        if (side == 0) idx_out[row] = (int)(unsigned)(pk & 0xFFFFFFFFu);
    }
}

// ---------------- Overflow rows: block per 4 rows, thread=code, coalesced cbT ----------------
__global__ __launch_bounds__(512) void vq_rescore_of(const float* __restrict__ zt,
                                                     const float* __restrict__ cbT,
                                                     const float* __restrict__ enb,
                                                     const float* __restrict__ znb,
                                                     const unsigned* __restrict__ ctr,
                                                     const unsigned* __restrict__ oflist,
                                                     int* __restrict__ idx_out) {
    __shared__ __align__(16) float zl[4][CDIM];
    __shared__ unsigned long long wmin[4][8];
    unsigned n = ctr[1]; if (n > 65536u) n = 65536u;
    const int t = threadIdx.x;
    const float en_t = enb[t];

    for (unsigned e0 = blockIdx.x << 2; e0 < n; e0 += gridDim.x << 2) {
        int nr = (int)(n - e0); if (nr > 4) nr = 4;
        // stage up to 4 zt rows, coalesced
        if (t < (nr << 6)) {
            int slot = t >> 6, f = t & 63;
            int row = (int)oflist[e0 + slot];
            float4 v = *reinterpret_cast<const float4*>(zt + ((size_t)row << 8) + (f << 2));
            *reinterpret_cast<float4*>(&zl[slot][f << 2]) = v;
        }
        __syncthreads();

        float a0 = 0.f, a1 = 0.f, a2 = 0.f, a3 = 0.f;
#pragma unroll 8
        for (int c = 0; c < CDIM; ++c) {
            float ev = cbT[((size_t)c << 9) + t];    // coalesced column read
            a0 += zl[0][c] * ev;   // each chain: ascending-c sequential FMA
            a1 += zl[1][c] * ev;   // (identical per-chain order to validated kernel)
            a2 += zl[2][c] * ev;
            a3 += zl[3][c] * ev;
        }
        float accv[4] = {a0, a1, a2, a3};

        for (int slot = 0; slot < nr; ++slot) {
            int row = (int)oflist[e0 + slot];
            float d = (znb[row] - 2.0f * accv[slot]) + en_t;
            unsigned long long pk =
                (((unsigned long long)__float_as_uint(d)) << 32) | (unsigned)t;
#pragma unroll
            for (int o = 1; o < 64; o <<= 1) {
                unsigned long long q2 = __shfl_xor(pk, o, 64);
                if (q2 < pk) pk = q2;
            }
            if ((t & 63) == 0) wmin[slot][t >> 6] = pk;
        }
        __syncthreads();
        if (t < nr) {
            unsigned long long best = wmin[t][0];
#pragma unroll
            for (int i = 1; i < 8; ++i) if (wmin[t][i] < best) best = wmin[t][i];
            idx_out[(int)oflist[e0 + t]] = (int)(unsigned)(best & 0xFFFFFFFFu);
        }
        __syncthreads();
    }
}

// ---------------- Fallback exact argmin (validated round-2 kernel) ----------------
__global__ __launch_bounds__(512) void vq_argmin(const float* __restrict__ z,
                                                 const float* __restrict__ cb,
                                                 const float* __restrict__ enorm,
                                                 int* __restrict__ out_idx) {
    __shared__ float zs[64][SZ];
    __shared__ float es[64][SZ];
    __shared__ float ens[K_CODES];
    __shared__ float zn[64];
    __shared__ float red_d[64][32];
    __shared__ int   red_i[64][32];

    const int t  = threadIdx.x;
    const int r0 = blockIdx.x * 64;
    const int b  = r0 >> 10;
    const int n0 = r0 & 1023;
    const float* zb = z + (size_t)b * CDIM * HW;

#pragma unroll
    for (int p = 0; p < 8; ++p) {
        int lin = p * 512 + t;
        int c   = lin >> 4;
        int i0  = (lin & 15) << 2;
        float4 v = *reinterpret_cast<const float4*>(zb + (size_t)c * HW + n0 + i0);
        zs[i0 + 0][c] = v.x; zs[i0 + 1][c] = v.y;
        zs[i0 + 2][c] = v.z; zs[i0 + 3][c] = v.w;
    }
    if (t < K_CODES) ens[t] = enorm[t];
    __syncthreads();

    if (t < 64) {
        float s0 = 0.f, s1 = 0.f, s2 = 0.f, s3 = 0.f;
        for (int c = 0; c < CDIM; c += 4) {
            float4 v = *reinterpret_cast<const float4*>(&zs[t][c]);
            s0 += v.x * v.x; s1 += v.y * v.y; s2 += v.z * v.z; s3 += v.w * v.w;
        }
        zn[t] = (s0 + s1) + (s2 + s3);
    }

    const int ty = t >> 5, tx = t & 31, row0 = ty * 4;
    float best_d[4]; int best_i[4];
#pragma unroll
    for (int i = 0; i < 4; ++i) { best_d[i] = 3.4e38f; best_i[i] = 0; }

    for (int K0 = 0; K0 < K_CODES; K0 += 64) {
        __syncthreads();
#pragma unroll
        for (int p = 0; p < 8; ++p) {
            int lin = p * 512 + t;
            int j = lin >> 6, c4 = (lin & 63) << 2;
            *reinterpret_cast<float4*>(&es[j][c4]) =
                *reinterpret_cast<const float4*>(cb + (size_t)(K0 + j) * CDIM + c4);
        }
        __syncthreads();

        float acc[4][2];
#pragma unroll
        for (int i = 0; i < 4; ++i) { acc[i][0] = 0.f; acc[i][1] = 0.f; }
#pragma unroll 4
        for (int k = 0; k < CDIM; k += 4) {
            float4 a0 = *reinterpret_cast<const float4*>(&zs[row0 + 0][k]);
            float4 a1 = *reinterpret_cast<const float4*>(&zs[row0 + 1][k]);
            float4 a2 = *reinterpret_cast<const float4*>(&zs[row0 + 2][k]);
            float4 a3 = *reinterpret_cast<const float4*>(&zs[row0 + 3][k]);
            float4 e0 = *reinterpret_cast<const float4*>(&es[tx][k]);
            float4 e1 = *reinterpret_cast<const float4*>(&es[tx + 32][k]);
            float4 aa[4] = {a0, a1, a2, a3};
#pragma unroll
            for (int i = 0; i < 4; ++i) {
#pragma unroll
                for (int j = 0; j < 2; ++j) {
                    float4 e = j ? e1 : e0;
                    acc[i][j] += aa[i].x * e.x; acc[i][j] += aa[i].y * e.y;
                    acc[i][j] += aa[i].z * e.z; acc[i][j] += aa[i].w * e.w;
                }
            }
        }
#pragma unroll
        for (int i = 0; i < 4; ++i) {
            float zni = zn[row0 + i];
#pragma unroll
            for (int j = 0; j < 2; ++j) {
                int code = K0 + j * 32 + tx;
                float d = (zni - 2.0f * acc[i][j]) + ens[code];
                if (d < best_d[i]) { best_d[i] = d; best_i[i] = code; }
            }
        }
    }
    __syncthreads();
#pragma unroll
    for (int i = 0; i < 4; ++i) {
        red_d[row0 + i][tx] = best_d[i];
        red_i[row0 + i][tx] = best_i[i];
    }
    __syncthreads();
    if (t < 64) {
        float bd = red_d[t][0]; int bi = red_i[t][0];
        for (int x = 1; x < 32; ++x) {
            float d = red_d[t][x]; int ii = red_i[t][x];
            if (d < bd || (d == bd && ii < bi)) { bd = d; bi = ii; }
        }
        out_idx[r0 + t] = bi;
    }
}

// ---------------- Gather: float4 stores, 1024 blocks ----------------
__global__ __launch_bounds__(256) void vq_gather(const float* __restrict__ cb,
                                                 const int* __restrict__ idx,
                                                 float* __restrict__ out) {
    const int blk = blockIdx.x;
    const int b = blk >> 4;
    const int q = blk & 15;
    const int t = threadIdx.x;
    int4 cd = reinterpret_cast<const int4*>(idx + (b << 10))[t];
    if (q == 0) {
        float4 f = make_float4((float)cd.x, (float)cd.y, (float)cd.z, (float)cd.w);
        reinterpret_cast<float4*>(out + (size_t)NBATCH * CDIM * HW + ((size_t)b << 10))[t] = f;
    }
    const int c0 = q << 4;
    const float* e0 = cb + (size_t)cd.x * CDIM + c0;
    const float* e1 = cb + (size_t)cd.y * CDIM + c0;
    const float* e2 = cb + (size_t)cd.z * CDIM + c0;
    const float* e3 = cb + (size_t)cd.w * CDIM + c0;
    float* ob = out + ((size_t)b * CDIM + c0) * HW + (t << 2);
#pragma unroll 4
    for (int c = 0; c < 16; ++c) {
        float4 v = make_float4(e0[c], e1[c], e2[c], e3[c]);
        *reinterpret_cast<float4*>(ob) = v;
        ob += HW;
    }
}

extern "C" void kernel_launch(void* const* d_in, const int* in_sizes, int n_in,
                              void* d_out, int out_size, void* d_ws, size_t ws_size,
                              hipStream_t stream) {
    const float* z  = (const float*)d_in[0];
    const float* cb = (const float*)d_in[1];
    float* out = (float*)d_out;
    float* zt  = (float*)d_out;   // z_q region (64 MiB) used as scratch, overwritten by gather

    // ws layout
    int*            idx   = (int*)d_ws;                                  // 262144 B
    float*          en    = (float*)((char*)d_ws + 262144);              // 2048 B
    unsigned short* cb16  = (unsigned short*)((char*)d_ws + 264192);     // 262144 B
    float*          znb   = (float*)((char*)d_ws + 526336);              // 262144 B
    unsigned short* codes = (unsigned short*)((char*)d_ws + 788480);     // 2097152 B
    unsigned*       mlist = (unsigned*)((char*)d_ws + 2885632);          // 262144 B
    unsigned*       ctr   = (unsigned*)((char*)d_ws + 3147776);          // 16 B
    unsigned*       oflist= (unsigned*)((char*)d_ws + 3147792);          // 262144 B
    float*          cbT   = (float*)((char*)d_ws + 3409936);             // 524288 B
    const size_t NEED_FULL = 3934224;

    if (ws_size >= NEED_FULL) {
        hipMemsetAsync(ctr, 0, 16, stream);
        vq_prep      <<<dim3(K_CODES), dim3(64),  0, stream>>>(cb, en, cb16);
        vq_cbt       <<<dim3(32),      dim3(256), 0, stream>>>(cb, cbT);
        vq_zn        <<<dim3(1024),    dim3(256), 0, stream>>>(z, znb, zt);
        vq_pass1     <<<dim3(512),     dim3(256), 0, stream>>>(z, cb16, codes, idx, mlist, oflist, ctr);
        vq_rescore2  <<<dim3(2048),    dim3(256), 0, stream>>>(zt, cb, en, znb, codes, ctr, mlist, idx);
        vq_rescore_of<<<dim3(512),     dim3(512), 0, stream>>>(zt, cbT, en, znb, ctr, oflist, idx);
    } else {
        vq_enorm  <<<dim3(K_CODES), dim3(64),  0, stream>>>(cb, en);
        vq_argmin <<<dim3(1024),    dim3(512), 0, stream>>>(z, cb, en, idx);
    }
    vq_gather<<<dim3(1024), dim3(256), 0, stream>>>(cb, idx, out);
}

// Round 11
// 167.355 us; speedup vs baseline: 1.4071x; 1.0618x over previous
//
#include <hip/hip_runtime.h>
#include <hip/hip_bf16.h>

#define K_CODES 512
#define CDIM    256
#define HW      1024
#define NBATCH  64
#define SZ      260   // validated LDS stride

typedef float  f32x16 __attribute__((ext_vector_type(16)));
typedef short  bf16x8 __attribute__((ext_vector_type(8)));
typedef __fp16 half2_t __attribute__((ext_vector_type(2)));

typedef __attribute__((address_space(1))) const unsigned int gld_src_t;
typedef __attribute__((address_space(3))) unsigned int       gld_dst_t;

__device__ __forceinline__ unsigned short f2bf(float x) {
    unsigned u = __float_as_uint(x);
    unsigned r = (u + 0x7FFFu + ((u >> 16) & 1u)) >> 16;   // RNE
    return (unsigned short)r;
}

// ---------------- Fused setup: zt+zn (blocks 0..1023), prep (1024..1151), cbT (1152..1183) ----------------
__global__ __launch_bounds__(256) void vq_setup(const float* __restrict__ z,
                                                const float* __restrict__ cb,
                                                float* __restrict__ zn_out,
                                                float* __restrict__ zt_out,
                                                float* __restrict__ enorm,
                                                unsigned short* __restrict__ cb16,
                                                float* __restrict__ cbT,
                                                unsigned* __restrict__ ctr) {
    __shared__ __align__(16) char sm[66560];
    const int t   = threadIdx.x;
    const int bid = blockIdx.x;

    if (bid < 1024) {
        // ---- z transpose + row norms (bit-identical validated staging/chain)
        float (*zs)[SZ] = reinterpret_cast<float(*)[SZ]>(sm);
        const int r0 = bid * 64;
        const int b  = r0 >> 10;
        const int n0 = r0 & 1023;
        const float* zb = z + (size_t)b * CDIM * HW;
#pragma unroll
        for (int p = 0; p < 16; ++p) {
            int lin = p * 256 + t;
            int c   = lin >> 4;
            int i0  = (lin & 15) << 2;
            float4 v = *reinterpret_cast<const float4*>(zb + (size_t)c * HW + n0 + i0);
            zs[i0 + 0][c] = v.x; zs[i0 + 1][c] = v.y;
            zs[i0 + 2][c] = v.z; zs[i0 + 3][c] = v.w;
        }
        __syncthreads();
        if (t < 64) {
            float s0 = 0.f, s1 = 0.f, s2 = 0.f, s3 = 0.f;
            for (int c = 0; c < CDIM; c += 4) {
                float4 v = *reinterpret_cast<const float4*>(&zs[t][c]);
                s0 += v.x * v.x; s1 += v.y * v.y; s2 += v.z * v.z; s3 += v.w * v.w;
            }
            zn_out[r0 + t] = (s0 + s1) + (s2 + s3);
        }
#pragma unroll
        for (int p = 0; p < 16; ++p) {
            int f   = p * 256 + t;
            int row = f >> 6;
            int c4  = (f & 63) << 2;
            float4 v = *reinterpret_cast<const float4*>(&zs[row][c4]);
            *reinterpret_cast<float4*>(zt_out + (((size_t)(r0 + row)) << 8) + c4) = v;
        }
    } else if (bid < 1152) {
        // ---- prep: 4 codes/block, one 64-lane wave-group per code (validated butterfly)
        if (bid == 1024 && t < 4) ctr[t] = 0;
        int code = ((bid - 1024) << 2) + (t >> 6);
        int l = t & 63;
        float4 v = *reinterpret_cast<const float4*>(cb + (size_t)code * CDIM + l * 4);
        float s = (v.x * v.x + v.y * v.y) + (v.z * v.z + v.w * v.w);
#pragma unroll
        for (int off = 1; off < 64; off <<= 1) s += __shfl_xor(s, off, 64);
        if (l == 0) enorm[code] = s;
        ushort4 o;
        o.x = f2bf(v.x); o.y = f2bf(v.y); o.z = f2bf(v.z); o.w = f2bf(v.w);
        *reinterpret_cast<ushort4*>(cb16 + (size_t)code * CDIM + l * 4) = o;
    } else {
        // ---- cbT: codebook transpose tile (identical to validated vq_cbt)
        float (*st)[65] = reinterpret_cast<float(*)[65]>(sm);
        const int bb = bid - 1152;
        const int k0 = (bb >> 2) << 6;
        const int c0 = (bb & 3) << 6;
#pragma unroll
        for (int q = 0; q < 4; ++q) {
            int lin = (q << 8) + t;
            int kr  = lin >> 4;
            int cc  = (lin & 15) << 2;
            float4 v = *reinterpret_cast<const float4*>(cb + (size_t)(k0 + kr) * CDIM + c0 + cc);
            st[kr][cc + 0] = v.x; st[kr][cc + 1] = v.y;
            st[kr][cc + 2] = v.z; st[kr][cc + 3] = v.w;
        }
        __syncthreads();
#pragma unroll
        for (int q = 0; q < 4; ++q) {
            int lin = (q << 8) + t;
            int cr  = lin >> 4;
            int kk  = (lin & 15) << 2;
            float4 v = make_float4(st[kk + 0][cr], st[kk + 1][cr],
                                   st[kk + 2][cr], st[kk + 3][cr]);
            *reinterpret_cast<float4*>(cbT + (size_t)(c0 + cr) * K_CODES + k0 + kk) = v;
        }
    }
}

// ---------------- Pass 1: single-sweep MFMA filter, f16 value store, O(cand) emission ----------------
// 128 rows/block, 256 thr (4 waves x 32 rows). 16 phases of 32 codes, async es ring.
__global__ __launch_bounds__(256, 2) void vq_pass1(const float* __restrict__ z,
                                                   const unsigned short* __restrict__ cb16,
                                                   unsigned short* __restrict__ codes_out,
                                                   int* __restrict__ idx_out,
                                                   unsigned* __restrict__ mlist,
                                                   unsigned* __restrict__ oflist,
                                                   unsigned* __restrict__ ctr) {
    __shared__ __align__(16) char smem[70144];
    unsigned short* zs    = (unsigned short*)smem;            // 64KB transient
    unsigned*       zsw   = (unsigned*)smem;
    unsigned short* es    = (unsigned short*)smem;            // reuse: 4 x 16KB ring
    unsigned short* candl = (unsigned short*)(smem + 65536);  // 128*16 u16
    unsigned*       cntl  = (unsigned*)(smem + 69632);        // 128 u32

    const int t = threadIdx.x;
    const int l = t & 63, w = t >> 6;          // 4 waves
    const int r0 = blockIdx.x << 7;            // 128 rows/block
    const int b  = r0 >> 10, n0 = r0 & 1023;
    const float* zb = z + (size_t)b * (CDIM * HW);

    // ---- stage z: transpose + bf16 (identical bit-path to validated rounds)
#pragma unroll
    for (int p = 0; p < 16; ++p) {
        int lin = (p << 8) + t;
        int c2  = lin >> 5;          // 0..127 (k-pairs)
        int iq  = lin & 31;          // 0..31  (row-quads)
        const float* g0 = zb + (size_t)(2 * c2) * HW + n0 + (iq << 2);
        float4 a  = *reinterpret_cast<const float4*>(g0);
        float4 bb = *reinterpret_cast<const float4*>(g0 + HW);
        int up = (((c2 >> 2) ^ (iq & 7)) << 2) + (c2 & 3);
        const float* ap = &a.x; const float* bp = &bb.x;
#pragma unroll
        for (int j = 0; j < 4; ++j) {
            unsigned pk = (unsigned)f2bf(ap[j]) | ((unsigned)f2bf(bp[j]) << 16);
            zsw[((iq << 2) + j) * 128 + up] = pk;
        }
    }
    __syncthreads();

    // ---- B-frags (z rows) into registers (identical to validated rounds)
    const int lrow = l & 31, lh = l >> 5;
    const int lf  = (lrow >> 2) & 7;
    const int row = (w << 5) + lrow;           // 0..127
    bf16x8 zf[16];
#pragma unroll
    for (int s = 0; s < 16; ++s) {
        int u = (2 * s + lh) ^ lf;
        zf[s] = *reinterpret_cast<const bf16x8*>(&zs[row * 256 + (u << 3)]);
    }
    float sa = 0.f;
#pragma unroll
    for (int s = 0; s < 16; ++s)
#pragma unroll
        for (int j = 0; j < 8; ++j)
            sa += fabsf(__uint_as_float(((unsigned)(unsigned short)zf[s][j]) << 16));
    sa += __shfl_xor(sa, 32, 64);

    __syncthreads();   // all zs reads done -> es ring may reuse region
    if (t < 128) cntl[t] = 0;

    // ---- async es stager: wave w fills chunks w*4..w*4+3 (1KB each) of a phase
    const int lq = l & 31, lhh = l >> 5;
    auto ISSUE = [&](int ph) {
#pragma unroll
        for (int j = 0; j < 4; ++j) {
            int chunk = (w << 2) + j;
            int lc    = (chunk << 1) + lhh;        // local code 0..31
            int su    = (lq - lc) & 31;            // pre-rotated source unit
            const unsigned short* gp = cb16 + (((size_t)((ph << 5) + lc)) << 8) + (su << 3);
            char* lp = smem + (((ph & 3) << 14) + (chunk << 10));
            __builtin_amdgcn_global_load_lds((gld_src_t*)gp, (gld_dst_t*)lp, 16, 0, 0);
        }
    };

    ISSUE(0); ISSUE(1);
    asm volatile("s_waitcnt vmcnt(4)" ::: "memory");
    __builtin_amdgcn_s_barrier();   // also publishes cntl zeroing

    float runmax = -3.4e38f;
    unsigned vst[128];               // 16 phases x 8 packed-f16 pairs (static idx after unroll)

#pragma unroll
    for (int p = 0; p < 16; ++p) {
        if (p + 2 < 16) ISSUE(p + 2);
        if (p >= 1) {
            if (p < 14)       asm volatile("s_waitcnt vmcnt(8)" ::: "memory");
            else if (p == 14) asm volatile("s_waitcnt vmcnt(4)" ::: "memory");
            else              asm volatile("s_waitcnt vmcnt(0)" ::: "memory");
            __builtin_amdgcn_s_barrier();
        }
        const unsigned short* eb = es + ((p & 3) << 13);

        f32x16 accA = {0.f,0.f,0.f,0.f,0.f,0.f,0.f,0.f,0.f,0.f,0.f,0.f,0.f,0.f,0.f,0.f};
        f32x16 accB = accA;
#pragma unroll
        for (int s = 0; s < 16; s += 2) {
            int u0 = (2 * s + lh + lrow) & 31;
            int u1 = (2 * s + 2 + lh + lrow) & 31;
            bf16x8 a0 = *reinterpret_cast<const bf16x8*>(&eb[(lrow << 8) + (u0 << 3)]);
            bf16x8 a1 = *reinterpret_cast<const bf16x8*>(&eb[(lrow << 8) + (u1 << 3)]);
            accA = __builtin_amdgcn_mfma_f32_32x32x16_bf16(a0, zf[s],     accA, 0, 0, 0);
            accB = __builtin_amdgcn_mfma_f32_32x32x16_bf16(a1, zf[s + 1], accB, 0, 0, 0);
        }

        float pm = -3.4e38f;
#pragma unroll
        for (int j = 0; j < 8; ++j) {
            float a = accA[2 * j]     + accB[2 * j];
            float c = accA[2 * j + 1] + accB[2 * j + 1];
            pm = fmaxf(pm, fmaxf(a, c));
            half2_t h = __builtin_amdgcn_cvt_pkrtz(a, c);   // RTZ f16 pack
            unsigned wrd; __builtin_memcpy(&wrd, &h, 4);
            vst[(p << 3) + j] = wrd;
        }
        runmax = fmaxf(runmax, pm);
    }

    // ---- threshold: validated margin + f16-storage slack (err <= |v|*2^-10 <= sa*1.92e-6)
    float rowmax = fmaxf(runmax, __shfl_xor(runmax, 32, 64));
    const float thr = rowmax - (sa * 1.9e-5f + 6.2e-4f);

    // ---- emission: scan stored values, O(candidates) LDS atomics
#pragma unroll
    for (int p = 0; p < 16; ++p) {
        const int cbase = (p << 5) + 4 * lh;
#pragma unroll
        for (int j = 0; j < 8; ++j) {
            unsigned wrd = vst[(p << 3) + j];
            half2_t h; __builtin_memcpy(&h, &wrd, 4);
            float a = (float)h[0];
            float c = (float)h[1];
            if (a >= thr) {
                int i = 2 * j;
                int code = cbase + (i & 3) + 8 * (i >> 2);
                unsigned pos = atomicAdd(&cntl[row], 1u);
                if (pos < 16u) candl[(row << 4) + pos] = (unsigned short)code;
            }
            if (c >= thr) {
                int i = 2 * j + 1;
                int code = cbase + (i & 3) + 8 * (i >> 2);
                unsigned pos = atomicAdd(&cntl[row], 1u);
                if (pos < 16u) candl[(row << 4) + pos] = (unsigned short)code;
            }
        }
    }
    __syncthreads();

    if (t < 128) {
        unsigned c = cntl[t];
        if (c == 1u) idx_out[r0 + t] = (int)candl[t << 4];
        bool multi = (c >= 2u && c <= 16u);
        bool ofl   = (c > 16u);
        unsigned long long m = __ballot(multi);
        int lane = t & 63;
        int rank = __popcll(m & ((1ull << lane) - 1ull));
        int tot  = __popcll(m);
        unsigned base = 0;
        if (lane == 0 && tot) base = atomicAdd(&ctr[0], (unsigned)tot);
        base = __shfl(base, 0, 64);
        if (multi) mlist[base + rank] = (unsigned)(r0 + t) | (c << 16);
        if (ofl) {
            unsigned pos = atomicAdd(&ctr[1], 1u);
            if (pos < 65536u) oflist[pos] = (unsigned)(r0 + t);
        }
    }
    reinterpret_cast<uint4*>(codes_out + ((size_t)r0 << 4))[t] =
        reinterpret_cast<const uint4*>(candl)[t];
}

// ---------------- Pass 2: exact fp32 rescore via contiguous zt rows ----------------
__global__ __launch_bounds__(256) void vq_rescore2(const float* __restrict__ zt,
                                                   const float* __restrict__ cb,
                                                   const float* __restrict__ enb,
                                                   const float* __restrict__ znb,
                                                   const unsigned short* __restrict__ codes_in,
                                                   const unsigned* __restrict__ ctr,
                                                   const unsigned* __restrict__ mlist,
                                                   int* __restrict__ idx_out) {
    const unsigned N = ctr[0];
    const unsigned total = N * 2u;
    unsigned i = blockIdx.x * 256u + threadIdx.x;
    for (; i < total; i += gridDim.x * 256u) {
        unsigned e   = mlist[i >> 1];
        int side     = (int)(i & 1u);
        int row      = (int)(e & 0xFFFFu);
        int cnt      = (int)(e >> 16);
        const float* zp = zt + ((size_t)row << 8);
        const float  zn = znb[row];
        unsigned long long pk = 0xFFFFFFFFFFFFFFFFull;

        for (int j = side; j < cnt; j += 2) {
            int code = (int)codes_in[((size_t)row << 4) + j];
            const float* ep = cb + ((size_t)code << 8);
            float acc = 0.f;
#pragma unroll 8
            for (int u = 0; u < 64; ++u) {
                float4 zv = *reinterpret_cast<const float4*>(zp + (u << 2));
                float4 ev = *reinterpret_cast<const float4*>(ep + (u << 2));
                acc += zv.x * ev.x;   // sequential fp32 FMA chain
                acc += zv.y * ev.y;   // (identical order to validated kernel)
                acc += zv.z * ev.z;
                acc += zv.w * ev.w;
            }
            float d = (zn - 2.0f * acc) + enb[code];
            unsigned long long q =
                (((unsigned long long)__float_as_uint(d)) << 32) | (unsigned)code;
            if (q < pk) pk = q;
        }
        unsigned long long q2 = __shfl_xor(pk, 1, 64);
        if (q2 < pk) pk = q2;
        if (side == 0) idx_out[row] = (int)(unsigned)(pk & 0xFFFFFFFFu);
    }
}

// ---------------- Overflow rows: block per 4 rows, thread=code, coalesced cbT ----------------
__global__ __launch_bounds__(512) void vq_rescore_of(const float* __restrict__ zt,
                                                     const float* __restrict__ cbT,
                                                     const float* __restrict__ enb,
                                                     const float* __restrict__ znb,
                                                     const unsigned* __restrict__ ctr,
                                                     const unsigned* __restrict__ oflist,
                                                     int* __restrict__ idx_out) {
    __shared__ __align__(16) float zl[4][CDIM];
    __shared__ unsigned long long wmin[4][8];
    unsigned n = ctr[1]; if (n > 65536u) n = 65536u;
    const int t = threadIdx.x;
    const float en_t = enb[t];

    for (unsigned e0 = blockIdx.x << 2; e0 < n; e0 += gridDim.x << 2) {
        int nr = (int)(n - e0); if (nr > 4) nr = 4;
        if (t < (nr << 6)) {
            int slot = t >> 6, f = t & 63;
            int row = (int)oflist[e0 + slot];
            float4 v = *reinterpret_cast<const float4*>(zt + ((size_t)row << 8) + (f << 2));
            *reinterpret_cast<float4*>(&zl[slot][f << 2]) = v;
        }
        __syncthreads();

        float a0 = 0.f, a1 = 0.f, a2 = 0.f, a3 = 0.f;
#pragma unroll 8
        for (int c = 0; c < CDIM; ++c) {
            float ev = cbT[((size_t)c << 9) + t];    // coalesced column read
            a0 += zl[0][c] * ev;   // each chain: ascending-c sequential FMA
            a1 += zl[1][c] * ev;   // (identical per-chain order to validated kernel)
            a2 += zl[2][c] * ev;
            a3 += zl[3][c] * ev;
        }
        float accv[4] = {a0, a1, a2, a3};

        for (int slot = 0; slot < nr; ++slot) {
            int row = (int)oflist[e0 + slot];
            float d = (znb[row] - 2.0f * accv[slot]) + en_t;
            unsigned long long pk =
                (((unsigned long long)__float_as_uint(d)) << 32) | (unsigned)t;
#pragma unroll
            for (int o = 1; o < 64; o <<= 1) {
                unsigned long long q2 = __shfl_xor(pk, o, 64);
                if (q2 < pk) pk = q2;
            }
            if ((t & 63) == 0) wmin[slot][t >> 6] = pk;
        }
        __syncthreads();
        if (t < nr) {
            unsigned long long best = wmin[t][0];
#pragma unroll
            for (int i = 1; i < 8; ++i) if (wmin[t][i] < best) best = wmin[t][i];
            idx_out[(int)oflist[e0 + t]] = (int)(unsigned)(best & 0xFFFFFFFFu);
        }
        __syncthreads();
    }
}

// ---------------- Fallback exact kernels (validated round-2 path) ----------------
__global__ __launch_bounds__(64) void vq_enorm(const float* __restrict__ cb,
                                               float* __restrict__ enorm) {
    int k = blockIdx.x;
    int l = threadIdx.x;
    float4 v = *reinterpret_cast<const float4*>(cb + (size_t)k * CDIM + l * 4);
    float s = (v.x * v.x + v.y * v.y) + (v.z * v.z + v.w * v.w);
#pragma unroll
    for (int off = 1; off < 64; off <<= 1) s += __shfl_xor(s, off, 64);
    if (l == 0) enorm[k] = s;
}

__global__ __launch_bounds__(512) void vq_argmin(const float* __restrict__ z,
                                                 const float* __restrict__ cb,
                                                 const float* __restrict__ enorm,
                                                 int* __restrict__ out_idx) {
    __shared__ float zs[64][SZ];
    __shared__ float es[64][SZ];
    __shared__ float ens[K_CODES];
    __shared__ float zn[64];
    __shared__ float red_d[64][32];
    __shared__ int   red_i[64][32];

    const int t  = threadIdx.x;
    const int r0 = blockIdx.x * 64;
    const int b  = r0 >> 10;
    const int n0 = r0 & 1023;
    const float* zb = z + (size_t)b * CDIM * HW;

#pragma unroll
    for (int p = 0; p < 8; ++p) {
        int lin = p * 512 + t;
        int c   = lin >> 4;
        int i0  = (lin & 15) << 2;
        float4 v = *reinterpret_cast<const float4*>(zb + (size_t)c * HW + n0 + i0);
        zs[i0 + 0][c] = v.x; zs[i0 + 1][c] = v.y;
        zs[i0 + 2][c] = v.z; zs[i0 + 3][c] = v.w;
    }
    if (t < K_CODES) ens[t] = enorm[t];
    __syncthreads();

    if (t < 64) {
        float s0 = 0.f, s1 = 0.f, s2 = 0.f, s3 = 0.f;
        for (int c = 0; c < CDIM; c += 4) {
            float4 v = *reinterpret_cast<const float4*>(&zs[t][c]);
            s0 += v.x * v.x; s1 += v.y * v.y; s2 += v.z * v.z; s3 += v.w * v.w;
        }
        zn[t] = (s0 + s1) + (s2 + s3);
    }

    const int ty = t >> 5, tx = t & 31, row0 = ty * 4;
    float best_d[4]; int best_i[4];
#pragma unroll
    for (int i = 0; i < 4; ++i) { best_d[i] = 3.4e38f; best_i[i] = 0; }

    for (int K0 = 0; K0 < K_CODES; K0 += 64) {
        __syncthreads();
#pragma unroll
        for (int p = 0; p < 8; ++p) {
            int lin = p * 512 + t;
            int j = lin >> 6, c4 = (lin & 63) << 2;
            *reinterpret_cast<float4*>(&es[j][c4]) =
                *reinterpret_cast<const float4*>(cb + (size_t)(K0 + j) * CDIM + c4);
        }
        __syncthreads();

        float acc[4][2];
#pragma unroll
        for (int i = 0; i < 4; ++i) { acc[i][0] = 0.f; acc[i][1] = 0.f; }
#pragma unroll 4
        for (int k = 0; k < CDIM; k += 4) {
            float4 a0 = *reinterpret_cast<const float4*>(&zs[row0 + 0][k]);
            float4 a1 = *reinterpret_cast<const float4*>(&zs[row0 + 1][k]);
            float4 a2 = *reinterpret_cast<const float4*>(&zs[row0 + 2][k]);
            float4 a3 = *reinterpret_cast<const float4*>(&zs[row0 + 3][k]);
            float4 e0 = *reinterpret_cast<const float4*>(&es[tx][k]);
            float4 e1 = *reinterpret_cast<const float4*>(&es[tx + 32][k]);
            float4 aa[4] = {a0, a1, a2, a3};
#pragma unroll
            for (int i = 0; i < 4; ++i) {
#pragma unroll
                for (int j = 0; j < 2; ++j) {
                    float4 e = j ? e1 : e0;
                    acc[i][j] += aa[i].x * e.x; acc[i][j] += aa[i].y * e.y;
                    acc[i][j] += aa[i].z * e.z; acc[i][j] += aa[i].w * e.w;
                }
            }
        }
#pragma unroll
        for (int i = 0; i < 4; ++i) {
            float zni = zn[row0 + i];
#pragma unroll
            for (int j = 0; j < 2; ++j) {
                int code = K0 + j * 32 + tx;
                float d = (zni - 2.0f * acc[i][j]) + ens[code];
                if (d < best_d[i]) { best_d[i] = d; best_i[i] = code; }
            }
        }
    }
    __syncthreads();
#pragma unroll
    for (int i = 0; i < 4; ++i) {
        red_d[row0 + i][tx] = best_d[i];
        red_i[row0 + i][tx] = best_i[i];
    }
    __syncthreads();
    if (t < 64) {
        float bd = red_d[t][0]; int bi = red_i[t][0];
        for (int x = 1; x < 32; ++x) {
            float d = red_d[t][x]; int ii = red_i[t][x];
            if (d < bd || (d == bd && ii < bi)) { bd = d; bi = ii; }
        }
        out_idx[r0 + t] = bi;
    }
}

// ---------------- Gather: float4 stores, 1024 blocks ----------------
__global__ __launch_bounds__(256) void vq_gather(const float* __restrict__ cb,
                                                 const int* __restrict__ idx,
                                                 float* __restrict__ out) {
    const int blk = blockIdx.x;
    const int b = blk >> 4;
    const int q = blk & 15;
    const int t = threadIdx.x;
    int4 cd = reinterpret_cast<const int4*>(idx + (b << 10))[t];
    if (q == 0) {
        float4 f = make_float4((float)cd.x, (float)cd.y, (float)cd.z, (float)cd.w);
        reinterpret_cast<float4*>(out + (size_t)NBATCH * CDIM * HW + ((size_t)b << 10))[t] = f;
    }
    const int c0 = q << 4;
    const float* e0 = cb + (size_t)cd.x * CDIM + c0;
    const float* e1 = cb + (size_t)cd.y * CDIM + c0;
    const float* e2 = cb + (size_t)cd.z * CDIM + c0;
    const float* e3 = cb + (size_t)cd.w * CDIM + c0;
    float* ob = out + ((size_t)b * CDIM + c0) * HW + (t << 2);
#pragma unroll 4
    for (int c = 0; c < 16; ++c) {
        float4 v = make_float4(e0[c], e1[c], e2[c], e3[c]);
        *reinterpret_cast<float4*>(ob) = v;
        ob += HW;
    }
}

extern "C" void kernel_launch(void* const* d_in, const int* in_sizes, int n_in,
                              void* d_out, int out_size, void* d_ws, size_t ws_size,
                              hipStream_t stream) {
    const float* z  = (const float*)d_in[0];
    const float* cb = (const float*)d_in[1];
    float* out = (float*)d_out;
    float* zt  = (float*)d_out;   // z_q region (64 MiB) used as scratch, overwritten by gather

    // ws layout
    int*            idx   = (int*)d_ws;                                  // 262144 B
    float*          en    = (float*)((char*)d_ws + 262144);              // 2048 B
    unsigned short* cb16  = (unsigned short*)((char*)d_ws + 264192);     // 262144 B
    float*          znb   = (float*)((char*)d_ws + 526336);              // 262144 B
    unsigned short* codes = (unsigned short*)((char*)d_ws + 788480);     // 2097152 B
    unsigned*       mlist = (unsigned*)((char*)d_ws + 2885632);          // 262144 B
    unsigned*       ctr   = (unsigned*)((char*)d_ws + 3147776);          // 16 B
    unsigned*       oflist= (unsigned*)((char*)d_ws + 3147792);          // 262144 B
    float*          cbT   = (float*)((char*)d_ws + 3409936);             // 524288 B
    const size_t NEED_FULL = 3934224;

    if (ws_size >= NEED_FULL) {
        vq_setup     <<<dim3(1184), dim3(256), 0, stream>>>(z, cb, znb, zt, en, cb16, cbT, ctr);
        vq_pass1     <<<dim3(512),  dim3(256), 0, stream>>>(z, cb16, codes, idx, mlist, oflist, ctr);
        vq_rescore2  <<<dim3(512),  dim3(256), 0, stream>>>(zt, cb, en, znb, codes, ctr, mlist, idx);
        vq_rescore_of<<<dim3(512),  dim3(512), 0, stream>>>(zt, cbT, en, znb, ctr, oflist, idx);
    } else {
        vq_enorm  <<<dim3(K_CODES), dim3(64),  0, stream>>>(cb, en);
        vq_argmin <<<dim3(1024),    dim3(512), 0, stream>>>(z, cb, en, idx);
    }
    vq_gather<<<dim3(1024), dim3(256), 0, stream>>>(cb, idx, out);
}